// Round 9
// baseline (400.451 us; speedup 1.0000x reference)
//
#include <hip/hip_runtime.h>
#include <hip/hip_bf16.h>
#include <math.h>

#define D 128
#define NND 50000
#define NE 800000
#define NB1 196        // scan blocks: 196*256 = 50176 >= 50000
#define TPITCH 152     // ushort pitch for node transpose tile (304 B = 19*16)

typedef __attribute__((ext_vector_type(8))) short shortx8;
typedef __attribute__((ext_vector_type(4))) float floatx4;
typedef __attribute__((ext_vector_type(4))) unsigned int uintx4;

__device__ __forceinline__ float silu_f(float v) {
    // v / (1+e^-v) with hardware rcp (1 ulp) instead of IEEE divide
    return v * __builtin_amdgcn_rcpf(1.0f + __expf(-v));
}
__device__ __forceinline__ unsigned short f2bf(float f) {
    union { float f; unsigned int u; } v; v.f = f;
    unsigned int u = v.u;
    u += 0x7fffu + ((u >> 16) & 1u);   // RNE
    return (unsigned short)(u >> 16);
}
__device__ __forceinline__ void unpk(unsigned int u, float& lo, float& hi) {
    union { unsigned int x; float f; } a, b;
    a.x = u << 16;
    b.x = u & 0xffff0000u;
    lo = a.f; hi = b.f;
}

// ---------------- zero (deg) ----------------
__global__ void zero_kernel(float4* __restrict__ p, int n4) {
    int i = blockIdx.x * blockDim.x + threadIdx.x;
    float4 z = make_float4(0.f, 0.f, 0.f, 0.f);
    for (; i < n4; i += gridDim.x * blockDim.x) p[i] = z;
}

// ---------------- CSR build ----------------
__global__ void hist_kernel(const int* __restrict__ ei, int* __restrict__ deg) {
    int e = blockIdx.x * 256 + threadIdx.x;     // NE = 3125*256 exactly
    atomicAdd(&deg[ei[e]], 1);
}

__global__ void scan1_kernel(const int* __restrict__ deg,
                             int* __restrict__ part, int* __restrict__ bsum) {
    __shared__ int s[256];
    const int tid = threadIdx.x;
    const int i = blockIdx.x * 256 + tid;
    int v = (i < NND) ? deg[i] : 0;
    s[tid] = v;
    __syncthreads();
    #pragma unroll
    for (int off = 1; off < 256; off <<= 1) {
        int t = (tid >= off) ? s[tid - off] : 0;
        __syncthreads();
        s[tid] += t;
        __syncthreads();
    }
    part[i] = s[tid] - v;                        // exclusive
    if (tid == 255) bsum[blockIdx.x] = s[255];
}

__global__ void scan2_kernel(const int* __restrict__ bsum, int* __restrict__ boff) {
    __shared__ int s[256];
    const int tid = threadIdx.x;
    int v = (tid < NB1) ? bsum[tid] : 0;
    s[tid] = v;
    __syncthreads();
    #pragma unroll
    for (int off = 1; off < 256; off <<= 1) {
        int t = (tid >= off) ? s[tid - off] : 0;
        __syncthreads();
        s[tid] += t;
        __syncthreads();
    }
    if (tid < NB1) boff[tid] = s[tid] - v;       // exclusive
}

__global__ void scan3_kernel(const int* __restrict__ part, const int* __restrict__ boff,
                             int* __restrict__ rowptr, int* __restrict__ cursor) {
    int i = blockIdx.x * 256 + threadIdx.x;
    if (i < NND) {
        int v = part[i] + boff[i >> 8];
        rowptr[i] = v;
        cursor[i] = v;
    } else if (i == NND) {
        rowptr[NND] = NE;
    }
}

// scatter packed {col, row, dist2} into CSR order: ONE 16B store per edge
__global__ void scatter_kernel(const int* __restrict__ ei, const float* __restrict__ pos,
                               int* __restrict__ cursor,
                               uint4* __restrict__ epack) {
    int e = blockIdx.x * 256 + threadIdx.x;     // NE exact multiple of 256
    int r = ei[e], c = ei[NE + e];
    float dx = pos[r * 3 + 0] - pos[c * 3 + 0];
    float dy = pos[r * 3 + 1] - pos[c * 3 + 1];
    float dz = pos[r * 3 + 2] - pos[c * 3 + 2];
    float d2 = dx * dx + dy * dy + dz * dz;
    int slot = atomicAdd(&cursor[r], 1);
    uint4 v;
    v.x = (unsigned int)c;
    v.y = (unsigned int)r;
    v.z = __float_as_uint(d2);
    v.w = 0u;
    epack[slot] = v;
}

// ---------------- fused weight swizzle (all 4 matrices + wlf, 1 launch) ----
// Wf flat f = (((ks*4+quad)*128)+n*16+mrow)*8+j  <->  W[k=ks*32+quad*8+j][col=n*16+mrow]
__global__ void wswzall_kernel(const float* __restrict__ W1e, const float* __restrict__ W1n,
                               const float* __restrict__ W2e, const float* __restrict__ W2n,
                               unsigned short* __restrict__ w1f, unsigned short* __restrict__ w1nf,
                               unsigned short* __restrict__ w2f, unsigned short* __restrict__ w2nf,
                               unsigned short* __restrict__ wlf) {
    const int b = blockIdx.x;
    const float* W; unsigned short* Wf; int lb;
    if (b < 128)      { W = W1e; Wf = w1f;  lb = b; }
    else if (b < 256) { W = W1n; Wf = w1nf; lb = b - 128; }
    else if (b < 320) { W = W2e; Wf = w2f;  lb = b - 256; }
    else if (b < 384) { W = W2n; Wf = w2nf; lb = b - 320; }
    else {
        if (threadIdx.x < 128) wlf[threadIdx.x] = f2bf(W1e[256 * D + threadIdx.x]);
        return;
    }
    int f = lb * 256 + threadIdx.x;
    int j    = f & 7;
    int mrow = (f >> 3) & 15;
    int n    = (f >> 7) & 7;
    int rest = f >> 10;
    int quad = rest & 3;
    int ks   = rest >> 2;
    int col = n * 16 + mrow;
    int k   = ks * 32 + quad * 8 + j;
    Wf[f] = f2bf(W[k * D + col]);
}

// ---------------- A' = bf16(x@W1e_top + b1e), B = bf16(x@W1e_bot)  [MFMA] ----
// reads x f32 directly, converts A-frags inline (no separate xbf pass)
__global__ __launch_bounds__(256) void precompute_kernel(
        const float* __restrict__ x,
        const unsigned short* __restrict__ w1f,   // 256x128 swizzled
        const float* __restrict__ b1e,
        unsigned short* __restrict__ A,
        unsigned short* __restrict__ Bm) {
    const int t    = threadIdx.x;
    const int wv   = t >> 6;
    const int lane = t & 63;
    const int mrow = lane & 15;
    const int quad = lane >> 4;
    const int tile = blockIdx.x * 4 + wv;
    if (tile >= 3125) return;
    const int n0 = tile * 16;

    const float4* xrow = (const float4*)(x + ((size_t)(n0 + mrow) << 7));
    const uint4* wp   = (const uint4*)w1f;

    floatx4 accA[8], accB[8];
    #pragma unroll
    for (int n = 0; n < 8; ++n) {
        accA[n] = (floatx4){0.f, 0.f, 0.f, 0.f};
        accB[n] = (floatx4){0.f, 0.f, 0.f, 0.f};
    }

    #pragma unroll
    for (int s = 0; s < 4; ++s) {
        float4 xa = xrow[(s * 4 + quad) * 2 + 0];
        float4 xb = xrow[(s * 4 + quad) * 2 + 1];
        union { shortx8 v; __hip_bfloat162 p[4]; } af;
        af.p[0] = __float22bfloat162_rn(float2{xa.x, xa.y});
        af.p[1] = __float22bfloat162_rn(float2{xa.z, xa.w});
        af.p[2] = __float22bfloat162_rn(float2{xb.x, xb.y});
        af.p[3] = __float22bfloat162_rn(float2{xb.z, xb.w});
        const int baseA = (s * 4 + quad) * 128 + mrow;
        const int baseB = ((s + 4) * 4 + quad) * 128 + mrow;
        #pragma unroll
        for (int n = 0; n < 8; ++n) {
            union { uint4 u; shortx8 v; } bfA, bfB;
            bfA.u = wp[baseA + n * 16];
            bfB.u = wp[baseB + n * 16];
            accA[n] = __builtin_amdgcn_mfma_f32_16x16x32_bf16(af.v, bfA.v, accA[n], 0, 0, 0);
            accB[n] = __builtin_amdgcn_mfma_f32_16x16x32_bf16(af.v, bfB.v, accB[n], 0, 0, 0);
        }
    }

    float bb[8];
    #pragma unroll
    for (int n = 0; n < 8; ++n) bb[n] = b1e[n * 16 + mrow];

    #pragma unroll
    for (int reg = 0; reg < 4; ++reg) {
        const int node = n0 + quad * 4 + reg;
        #pragma unroll
        for (int n = 0; n < 8; ++n) {
            const int col = n * 16 + mrow;
            A[(size_t)node * D + col]  = f2bf(accA[n][reg] + bb[n]);
            Bm[(size_t)node * D + col] = f2bf(accB[n][reg]);
        }
    }
}

// ---------------- E1: edge MLP, 2 tiles (32 edges) per wave ----------------
// 800000/32 = 25000 waves, 6250 blocks, no masking. Layer-1 activations for
// BOTH tiles are computed first (af0/af1); the combined k-loop then loads
// each W2f fragment ONCE and feeds two independent MFMAs — halving per-edge
// weight traffic through L1 (R8 analysis: W2f re-reads were ~32KB/wave, the
// dominant TCP load) and doubling MFMA-chain ILP.
// ef written with per-row column permutation p = mrow*8 + n (logical col
// k = n*16 + mrow) -> 4 fully-coalesced 16B stores per lane per tile.
__global__ __launch_bounds__(256, 3) void edgemlp_kernel(
        const unsigned short* __restrict__ Abf,
        const unsigned short* __restrict__ Bbf,
        const uint4* __restrict__ epack,
        const unsigned short* __restrict__ wlf,
        const unsigned short* __restrict__ W2f,
        const float* __restrict__ b2e,
        unsigned short* __restrict__ ef) {
    const int t    = threadIdx.x;
    const int wv   = t >> 6;
    const int lane = t & 63;
    const int mrow = lane & 15;
    const int quad = lane >> 4;
    const int e0   = (blockIdx.x * 4 + wv) * 32;   // 6250 blocks exact
    const int ea   = e0 + mrow;                    // tile-0 edge of this lane
    const int eb   = e0 + 16 + mrow;               // tile-1 edge

    const uint4 epa = epack[ea];
    const uint4 epb = epack[eb];
    const int   ca  = (int)epa.x, ra = (int)epa.y;
    const int   cb  = (int)epb.x, rb = (int)epb.y;
    const float d2a = __uint_as_float(epa.z);
    const float d2b = __uint_as_float(epb.z);

    const uint4* arowa = (const uint4*)(Abf + ((size_t)ra << 7));
    const uint4* browa = (const uint4*)(Bbf + ((size_t)ca << 7));
    const uint4* arowb = (const uint4*)(Abf + ((size_t)rb << 7));
    const uint4* browb = (const uint4*)(Bbf + ((size_t)cb << 7));
    const uint4* wlq   = (const uint4*)wlf;
    const uint4* w2p   = (const uint4*)W2f;

    // hoist all A/B/wl loads for both tiles: 20 scattered loads in flight
    uint4 au0[4], bu0[4], au1[4], bu1[4], wu[4];
    #pragma unroll
    for (int s = 0; s < 4; ++s) {
        au0[s] = arowa[s * 4 + quad];
        bu0[s] = browa[s * 4 + quad];
        au1[s] = arowb[s * 4 + quad];
        bu1[s] = browb[s * 4 + quad];
        wu[s]  = wlq[s * 4 + quad];
    }

    // layer-1 for both tiles -> bf16 A-frags
    shortx8 af0[4], af1[4];
    #pragma unroll
    for (int s = 0; s < 4; ++s) {
        float w0, w1, w2, w3, w4, w5, w6, w7;
        unpk(wu[s].x, w0, w1); unpk(wu[s].y, w2, w3);
        unpk(wu[s].z, w4, w5); unpk(wu[s].w, w6, w7);
        {
            float a0, a1, a2, a3, a4, a5, a6, a7;
            float q0, q1, q2, q3, q4, q5, q6, q7;
            unpk(au0[s].x, a0, a1); unpk(au0[s].y, a2, a3);
            unpk(au0[s].z, a4, a5); unpk(au0[s].w, a6, a7);
            unpk(bu0[s].x, q0, q1); unpk(bu0[s].y, q2, q3);
            unpk(bu0[s].z, q4, q5); unpk(bu0[s].w, q6, q7);
            float h0 = silu_f(fmaf(d2a, w0, a0 + q0));
            float h1 = silu_f(fmaf(d2a, w1, a1 + q1));
            float h2 = silu_f(fmaf(d2a, w2, a2 + q2));
            float h3 = silu_f(fmaf(d2a, w3, a3 + q3));
            float h4 = silu_f(fmaf(d2a, w4, a4 + q4));
            float h5 = silu_f(fmaf(d2a, w5, a5 + q5));
            float h6 = silu_f(fmaf(d2a, w6, a6 + q6));
            float h7 = silu_f(fmaf(d2a, w7, a7 + q7));
            union { shortx8 v; __hip_bfloat162 p[4]; } af;
            af.p[0] = __float22bfloat162_rn(float2{h0, h1});
            af.p[1] = __float22bfloat162_rn(float2{h2, h3});
            af.p[2] = __float22bfloat162_rn(float2{h4, h5});
            af.p[3] = __float22bfloat162_rn(float2{h6, h7});
            af0[s] = af.v;
        }
        {
            float a0, a1, a2, a3, a4, a5, a6, a7;
            float q0, q1, q2, q3, q4, q5, q6, q7;
            unpk(au1[s].x, a0, a1); unpk(au1[s].y, a2, a3);
            unpk(au1[s].z, a4, a5); unpk(au1[s].w, a6, a7);
            unpk(bu1[s].x, q0, q1); unpk(bu1[s].y, q2, q3);
            unpk(bu1[s].z, q4, q5); unpk(bu1[s].w, q6, q7);
            float h0 = silu_f(fmaf(d2b, w0, a0 + q0));
            float h1 = silu_f(fmaf(d2b, w1, a1 + q1));
            float h2 = silu_f(fmaf(d2b, w2, a2 + q2));
            float h3 = silu_f(fmaf(d2b, w3, a3 + q3));
            float h4 = silu_f(fmaf(d2b, w4, a4 + q4));
            float h5 = silu_f(fmaf(d2b, w5, a5 + q5));
            float h6 = silu_f(fmaf(d2b, w6, a6 + q6));
            float h7 = silu_f(fmaf(d2b, w7, a7 + q7));
            union { shortx8 v; __hip_bfloat162 p[4]; } af;
            af.p[0] = __float22bfloat162_rn(float2{h0, h1});
            af.p[1] = __float22bfloat162_rn(float2{h2, h3});
            af.p[2] = __float22bfloat162_rn(float2{h4, h5});
            af.p[3] = __float22bfloat162_rn(float2{h6, h7});
            af1[s] = af.v;
        }
    }

    // combined layer-2: each W2f fragment loaded once, feeds both tiles
    floatx4 acc0[8], acc1[8];
    #pragma unroll
    for (int k = 0; k < 8; ++k) {
        acc0[k] = (floatx4){0.f, 0.f, 0.f, 0.f};
        acc1[k] = (floatx4){0.f, 0.f, 0.f, 0.f};
    }
    #pragma unroll
    for (int s = 0; s < 4; ++s) {
        const int base = (s * 4 + quad) * 128 + mrow;
        #pragma unroll
        for (int k = 0; k < 8; ++k) {
            union { uint4 u; shortx8 v; } bf;
            bf.u = w2p[base + k * 16];
            acc0[k] = __builtin_amdgcn_mfma_f32_16x16x32_bf16(af0[s], bf.v, acc0[k], 0, 0, 0);
            acc1[k] = __builtin_amdgcn_mfma_f32_16x16x32_bf16(af1[s], bf.v, acc1[k], 0, 0, 0);
        }
    }

    float bias[8];
    #pragma unroll
    for (int k = 0; k < 8; ++k) bias[k] = b2e[k * 16 + mrow];

    #pragma unroll
    for (int reg = 0; reg < 4; ++reg) {
        const int edge0 = e0 + quad * 4 + reg;
        union { uint4 u; __hip_bfloat162 p[4]; } ov;
        #pragma unroll
        for (int n = 0; n < 4; ++n) {
            float v0 = silu_f(acc0[2 * n + 0][reg] + bias[2 * n + 0]);
            float v1 = silu_f(acc0[2 * n + 1][reg] + bias[2 * n + 1]);
            ov.p[n] = __float22bfloat162_rn(float2{v0, v1});
        }
        *(uint4*)(ef + (((size_t)edge0) << 7) + mrow * 8) = ov.u;
    }
    #pragma unroll
    for (int reg = 0; reg < 4; ++reg) {
        const int edge1 = e0 + 16 + quad * 4 + reg;
        union { uint4 u; __hip_bfloat162 p[4]; } ov;
        #pragma unroll
        for (int n = 0; n < 4; ++n) {
            float v0 = silu_f(acc1[2 * n + 0][reg] + bias[2 * n + 0]);
            float v1 = silu_f(acc1[2 * n + 1][reg] + bias[2 * n + 1]);
            ov.p[n] = __float22bfloat162_rn(float2{v0, v1});
        }
        *(uint4*)(ef + (((size_t)edge1) << 7) + mrow * 8) = ov.u;
    }
}

// ---------------- E2: segmented sum over CSR ef rows (wave = node) ----------
// 16B/lane loads: one wave-load covers 4 rows (1024B contiguous). Sums
// reduced across the 4 sub-groups; lanes 0-15 write the canonical f32 row.
// ef loads are NON-TEMPORAL (dead after read; keep L3 for node_kernel).
__global__ __launch_bounds__(256) void aggsum_kernel(
        const unsigned short* __restrict__ ef,
        const int* __restrict__ rowptr,
        float* __restrict__ aggf) {
    const int t    = threadIdx.x;
    const int lane = t & 63;
    const int node = blockIdx.x * 4 + (t >> 6);  // 12500 * 4 = 50000 exact
    const int start = rowptr[node];
    const int end   = rowptr[node + 1];
    const int sub  = lane >> 4;                  // row within 4-row block
    const int j    = lane & 15;                  // 16B chunk within row

    const uintx4* ef4 = (const uintx4*)ef;       // row = 16 uintx4

    float s[8];
    #pragma unroll
    for (int i = 0; i < 8; ++i) s[i] = 0.f;

    for (int e = start; e < end; e += 4) {
        const int  er    = e + sub;
        const bool valid = er < end;
        const int  safe  = valid ? er : start;
        uintx4 u = __builtin_nontemporal_load(ef4 + (size_t)safe * 16 + j);
        float f0, f1, f2, f3, f4, f5, f6, f7;
        unpk(u.x, f0, f1); unpk(u.y, f2, f3);
        unpk(u.z, f4, f5); unpk(u.w, f6, f7);
        if (valid) {
            s[0] += f0; s[1] += f1; s[2] += f2; s[3] += f3;
            s[4] += f4; s[5] += f5; s[6] += f6; s[7] += f7;
        }
    }
    #pragma unroll
    for (int i = 0; i < 8; ++i) {
        s[i] += __shfl_xor(s[i], 16);
        s[i] += __shfl_xor(s[i], 32);
    }
    if (sub == 0) {
        // permuted position p = j*8 + i  ->  canonical col k = i*16 + j
        float* dst = aggf + ((size_t)node << 7) + j;
        #pragma unroll
        for (int i = 0; i < 8; ++i) dst[i * 16] = s[i];
    }
}

// ---------------- fallback: fused edge MLP + aggregation (f32 agg out) -----
__global__ __launch_bounds__(256, 2) void edgeagg_kernel(
        const unsigned short* __restrict__ Abf,
        const unsigned short* __restrict__ Bbf,
        const int* __restrict__ rowptr,
        const uint4* __restrict__ epack,
        const unsigned short* __restrict__ wlf,
        const unsigned short* __restrict__ W2f,
        const float* __restrict__ b2e,
        float* __restrict__ aggf) {
    const int t    = threadIdx.x;
    const int wv   = t >> 6;
    const int lane = t & 63;
    const int mrow = lane & 15;
    const int quad = lane >> 4;
    const int node = blockIdx.x * 4 + wv;        // 12500 * 4 = 50000 exact

    const int start = rowptr[node];
    const int d     = rowptr[node + 1] - start;

    const uint4* arow = (const uint4*)(Abf + ((size_t)node << 7));
    const uint4* wlq  = (const uint4*)wlf;
    uint4 au[4], wlu[4];
    #pragma unroll
    for (int s = 0; s < 4; ++s) {
        au[s]  = arow[s * 4 + quad];
        wlu[s] = wlq[s * 4 + quad];
    }
    float bias[8];
    #pragma unroll
    for (int k = 0; k < 8; ++k) bias[k] = b2e[k * 16 + mrow];

    float nacc[8];
    #pragma unroll
    for (int k = 0; k < 8; ++k) nacc[k] = 0.f;

    const uint4* w2p = (const uint4*)W2f;

    for (int tb = 0; tb < d; tb += 16) {
        const int  ei16 = tb + mrow;
        const bool ve   = ei16 < d;
        const int  idx  = start + (ve ? ei16 : 0);
        const uint4 ep  = epack[idx];
        const int  c    = (int)ep.x;
        float d2        = __uint_as_float(ep.z);
        d2 = ve ? d2 : 0.f;
        const uint4* brow = (const uint4*)(Bbf + ((size_t)c << 7));

        floatx4 acc[8];
        #pragma unroll
        for (int k = 0; k < 8; ++k) acc[k] = (floatx4){0.f, 0.f, 0.f, 0.f};

        #pragma unroll
        for (int s = 0; s < 4; ++s) {
            uint4 bu = brow[s * 4 + quad];

            float a0, a1, a2, a3, a4, a5, a6, a7;
            float q0, q1, q2, q3, q4, q5, q6, q7;
            float w0, w1, w2, w3, w4, w5, w6, w7;
            unpk(au[s].x, a0, a1); unpk(au[s].y, a2, a3);
            unpk(au[s].z, a4, a5); unpk(au[s].w, a6, a7);
            unpk(bu.x, q0, q1); unpk(bu.y, q2, q3);
            unpk(bu.z, q4, q5); unpk(bu.w, q6, q7);
            unpk(wlu[s].x, w0, w1); unpk(wlu[s].y, w2, w3);
            unpk(wlu[s].z, w4, w5); unpk(wlu[s].w, w6, w7);

            float h0 = silu_f(fmaf(d2, w0, a0 + q0));
            float h1 = silu_f(fmaf(d2, w1, a1 + q1));
            float h2 = silu_f(fmaf(d2, w2, a2 + q2));
            float h3 = silu_f(fmaf(d2, w3, a3 + q3));
            float h4 = silu_f(fmaf(d2, w4, a4 + q4));
            float h5 = silu_f(fmaf(d2, w5, a5 + q5));
            float h6 = silu_f(fmaf(d2, w6, a6 + q6));
            float h7 = silu_f(fmaf(d2, w7, a7 + q7));

            union { shortx8 v; __hip_bfloat162 p[4]; } af;
            af.p[0] = __float22bfloat162_rn(float2{h0, h1});
            af.p[1] = __float22bfloat162_rn(float2{h2, h3});
            af.p[2] = __float22bfloat162_rn(float2{h4, h5});
            af.p[3] = __float22bfloat162_rn(float2{h6, h7});

            const int base = (s * 4 + quad) * 128 + mrow;
            #pragma unroll
            for (int k = 0; k < 8; ++k) {
                union { uint4 u; shortx8 v; } bf;
                bf.u = w2p[base + k * 16];
                acc[k] = __builtin_amdgcn_mfma_f32_16x16x32_bf16(af.v, bf.v, acc[k], 0, 0, 0);
            }
        }

        #pragma unroll
        for (int reg = 0; reg < 4; ++reg) {
            const bool vr = (tb + quad * 4 + reg) < d;
            #pragma unroll
            for (int k = 0; k < 8; ++k)
                nacc[k] += vr ? silu_f(acc[k][reg] + bias[k]) : 0.f;
        }
    }

    #pragma unroll
    for (int k = 0; k < 8; ++k) {
        float v = nacc[k];
        v += __shfl_xor(v, 16);
        v += __shfl_xor(v, 32);
        nacc[k] = v;
    }
    const int n8a = quad * 2, n8b = quad * 2 + 1;
    aggf[(size_t)node * D + n8a * 16 + mrow] = nacc[n8a];
    aggf[(size_t)node * D + n8b * 16 + mrow] = nacc[n8b];
}

// ---------------- node MLP + residual + LayerNorm  [MFMA] ----------------
// 1 wave per block, block = 16 nodes. Stage1 K=256 ([x|agg] bf16, converted
// inline from f32), transpose via LDS (304 B pitch), stage2 K=128, epilogue
// residual + LN via quad shfl.
__global__ __launch_bounds__(64) void node_kernel(
        const float* __restrict__ aggf,
        const unsigned short* __restrict__ w1nf,  // 256x128 swizzled
        const float* __restrict__ b1n,
        const unsigned short* __restrict__ w2nf,  // 128x128 swizzled
        const float* __restrict__ b2n,
        const float* __restrict__ x,
        const float* __restrict__ gamma,
        const float* __restrict__ beta,
        float* __restrict__ out) {
    __shared__ __align__(16) unsigned short ts[16 * TPITCH];
    const int lane = threadIdx.x;
    const int mrow = lane & 15;
    const int quad = lane >> 4;
    const int n0 = blockIdx.x * 16;      // 3125 blocks exact

    const float4* xrow  = (const float4*)(x + ((size_t)(n0 + mrow) << 7));
    const float4* growf = (const float4*)(aggf + ((size_t)(n0 + mrow) << 7));
    const uint4*  w1p   = (const uint4*)w1nf;
    const uint4*  w2p   = (const uint4*)w2nf;

    floatx4 acc[8];
    #pragma unroll
    for (int n = 0; n < 8; ++n) {
        float b = b1n[n * 16 + mrow];
        acc[n] = (floatx4){b, b, b, b};
    }

    #pragma unroll
    for (int s = 0; s < 4; ++s) {
        float4 xa = xrow[(s * 4 + quad) * 2 + 0];
        float4 xb = xrow[(s * 4 + quad) * 2 + 1];
        union { shortx8 v; __hip_bfloat162 p[4]; } af;
        af.p[0] = __float22bfloat162_rn(float2{xa.x, xa.y});
        af.p[1] = __float22bfloat162_rn(float2{xa.z, xa.w});
        af.p[2] = __float22bfloat162_rn(float2{xb.x, xb.y});
        af.p[3] = __float22bfloat162_rn(float2{xb.z, xb.w});
        const int base = (s * 4 + quad) * 128 + mrow;
        #pragma unroll
        for (int n = 0; n < 8; ++n) {
            union { uint4 u; shortx8 v; } bf;
            bf.u = w1p[base + n * 16];
            acc[n] = __builtin_amdgcn_mfma_f32_16x16x32_bf16(af.v, bf.v, acc[n], 0, 0, 0);
        }
    }
    #pragma unroll
    for (int s = 0; s < 4; ++s) {
        float4 g0 = growf[(s * 4 + quad) * 2 + 0];
        float4 g1 = growf[(s * 4 + quad) * 2 + 1];
        union { shortx8 v; __hip_bfloat162 p[4]; } af;
        af.p[0] = __float22bfloat162_rn(float2{g0.x, g0.y});
        af.p[1] = __float22bfloat162_rn(float2{g0.z, g0.w});
        af.p[2] = __float22bfloat162_rn(float2{g1.x, g1.y});
        af.p[3] = __float22bfloat162_rn(float2{g1.z, g1.w});
        const int base = ((s + 4) * 4 + quad) * 128 + mrow;
        #pragma unroll
        for (int n = 0; n < 8; ++n) {
            union { uint4 u; shortx8 v; } bf;
            bf.u = w1p[base + n * 16];
            acc[n] = __builtin_amdgcn_mfma_f32_16x16x32_bf16(af.v, bf.v, acc[n], 0, 0, 0);
        }
    }

    // silu -> LDS (row-major [m][col], transpose for stage-2 A-frags)
    #pragma unroll
    for (int reg = 0; reg < 4; ++reg) {
        const int m = quad * 4 + reg;
        #pragma unroll
        for (int n = 0; n < 8; ++n)
            ts[m * TPITCH + n * 16 + mrow] = f2bf(silu_f(acc[n][reg]));
    }
    __syncthreads();   // single wave: cheap; guarantees LDS RAW ordering

    floatx4 acc2[8];
    #pragma unroll
    for (int n = 0; n < 8; ++n) {
        float b = b2n[n * 16 + mrow];
        acc2[n] = (floatx4){b, b, b, b};
    }
    #pragma unroll
    for (int s = 0; s < 4; ++s) {
        shortx8 af2 = *(const shortx8*)((const char*)ts +
                        mrow * (TPITCH * 2) + (s * 4 + quad) * 16);
        const int base = (s * 4 + quad) * 128 + mrow;
        #pragma unroll
        for (int n = 0; n < 8; ++n) {
            union { uint4 u; shortx8 v; } bf;
            bf.u = w2p[base + n * 16];
            acc2[n] = __builtin_amdgcn_mfma_f32_16x16x32_bf16(af2, bf.v, acc2[n], 0, 0, 0);
        }
    }

    // epilogue: residual + LayerNorm (reduce over the 16 lanes of each quad)
    float g[8], bt[8];
    #pragma unroll
    for (int n = 0; n < 8; ++n) {
        g[n]  = gamma[n * 16 + mrow];
        bt[n] = beta[n * 16 + mrow];
    }
    #pragma unroll
    for (int reg = 0; reg < 4; ++reg) {
        const int node = n0 + quad * 4 + reg;
        float u[8];
        float s1 = 0.f, s2 = 0.f;
        #pragma unroll
        for (int n = 0; n < 8; ++n) {
            u[n] = acc2[n][reg] + x[(size_t)node * D + n * 16 + mrow];
            s1 += u[n];
            s2 += u[n] * u[n];
        }
        #pragma unroll
        for (int off = 1; off < 16; off <<= 1) {
            s1 += __shfl_xor(s1, off);
            s2 += __shfl_xor(s2, off);
        }
        const float mu  = s1 * (1.f / 128.f);
        const float var = s2 * (1.f / 128.f) - mu * mu;
        const float rs  = rsqrtf(var + 1e-5f);
        #pragma unroll
        for (int n = 0; n < 8; ++n)
            out[(size_t)node * D + n * 16 + mrow] = (u[n] - mu) * rs * g[n] + bt[n];
    }
}

extern "C" void kernel_launch(void* const* d_in, const int* in_sizes, int n_in,
                              void* d_out, int out_size, void* d_ws, size_t ws_size,
                              hipStream_t stream) {
    const float* x     = (const float*)d_in[0];
    const float* pos   = (const float*)d_in[1];
    const int*   ei    = (const int*)d_in[2];
    const float* W1e   = (const float*)d_in[3];
    const float* b1e   = (const float*)d_in[4];
    const float* W2e   = (const float*)d_in[5];
    const float* b2e   = (const float*)d_in[6];
    const float* W1n   = (const float*)d_in[7];
    const float* b1n   = (const float*)d_in[8];
    const float* W2n   = (const float*)d_in[9];
    const float* b2n   = (const float*)d_in[10];
    const float* gamma = (const float*)d_in[11];
    const float* beta  = (const float*)d_in[12];
    float* out = (float*)d_out;

    // ws layout. Lifetimes: Abf/Bbf die after edgemlp; aggf (25.6 MB f32)
    // aliases Abf+Bbf exactly in the bigws path. Footprint ~244 MB < 256 MiB.
    int*            deg    = (int*)d_ws;                              // 50176
    int*            part   = deg + 50176;
    int*            bsum   = part + 50176;
    int*            boff   = bsum + 256;
    int*            rowptr = boff + 256;                              // 50004
    int*            cursor = rowptr + 50004;                          // 50000
    // 200868 ints = 803472 B, divisible by 16 -> epack aligned
    uint4*          epack  = (uint4*)(cursor + 50000);                // 12.8 MB
    unsigned short* Abf    = (unsigned short*)(epack + NE);           // 12.8 MB
    unsigned short* Bbf    = Abf + (size_t)NND * D;                   // 12.8 MB
    unsigned short* w1f    = Bbf + (size_t)NND * D;                   // 64 KB (256x128)
    unsigned short* w1nf   = w1f + 256 * D;                           // 64 KB (256x128)
    unsigned short* w2f    = w1nf + 256 * D;                          // 32 KB (128x128)
    unsigned short* w2nf   = w2f + D * D;                             // 32 KB (128x128)
    unsigned short* wlf    = w2nf + D * D;                            // 256 B
    unsigned short* ef     = wlf + 128;                               // 204.8 MB (bf16 edge feats)

    const size_t need_big = (size_t)((char*)(ef + (size_t)NE * D) - (char*)d_ws);
    const bool bigws = ws_size >= need_big;

    // aggf: alias dead Abf/Bbf (bigws) or the unused ef slot (fallback)
    float* aggf = bigws ? (float*)Abf : (float*)ef;

    // zero deg only
    zero_kernel<<<49, 256, 0, stream>>>((float4*)deg, 50176 / 4);

    // CSR build
    hist_kernel<<<NE / 256, 256, 0, stream>>>(ei, deg);
    scan1_kernel<<<NB1, 256, 0, stream>>>(deg, part, bsum);
    scan2_kernel<<<1, 256, 0, stream>>>(bsum, boff);
    scan3_kernel<<<197, 256, 0, stream>>>(part, boff, rowptr, cursor);
    scatter_kernel<<<NE / 256, 256, 0, stream>>>(ei, pos, cursor, epack);

    // fused weight swizzles (1 launch)
    wswzall_kernel<<<385, 256, 0, stream>>>(W1e, W1n, W2e, W2n,
                                            w1f, w1nf, w2f, w2nf, wlf);

    // A'/B precompute (MFMA, reads x f32 directly)
    precompute_kernel<<<782, 256, 0, stream>>>(x, w1f, b1e, Abf, Bbf);

    if (bigws) {
        // E1: edge MLP, 2 tiles/wave -> ef (CSR order, col-permuted rows)
        edgemlp_kernel<<<NE / 128, 256, 0, stream>>>(Abf, Bbf, epack,
                                                     wlf, w2f, b2e, ef);
        // E2: segmented sum -> aggf (canonical f32 layout; aliases dead Abf/Bbf)
        aggsum_kernel<<<NND / 4, 256, 0, stream>>>(ef, rowptr, aggf);
    } else {
        // fallback: fused per-node path (workspace too small for ef)
        edgeagg_kernel<<<NND / 4, 256, 0, stream>>>(Abf, Bbf, rowptr, epack,
                                                    wlf, w2f, b2e, aggf);
    }

    // node MLP + residual + LN (MFMA)
    node_kernel<<<NND / 16, 64, 0, stream>>>(aggf, w1nf, b1n, w2nf, b2n,
                                             x, gamma, beta, out);
}

// Round 10
// 347.404 us; speedup vs baseline: 1.1527x; 1.1527x over previous
//
#include <hip/hip_runtime.h>
#include <hip/hip_bf16.h>
#include <math.h>

#define D 128
#define NND 50000
#define NE 800000
#define NB1 196        // scan blocks: 196*256 = 50176 >= 50000
#define TPITCH 152     // ushort pitch for node transpose tile (304 B = 19*16)

typedef __attribute__((ext_vector_type(8))) short shortx8;
typedef __attribute__((ext_vector_type(4))) float floatx4;

__device__ __forceinline__ float silu_f(float v) {
    // v / (1+e^-v) with hardware rcp (1 ulp) instead of IEEE divide
    return v * __builtin_amdgcn_rcpf(1.0f + __expf(-v));
}
__device__ __forceinline__ unsigned short f2bf(float f) {
    union { float f; unsigned int u; } v; v.f = f;
    unsigned int u = v.u;
    u += 0x7fffu + ((u >> 16) & 1u);   // RNE
    return (unsigned short)(u >> 16);
}
__device__ __forceinline__ void unpk(unsigned int u, float& lo, float& hi) {
    union { unsigned int x; float f; } a, b;
    a.x = u << 16;
    b.x = u & 0xffff0000u;
    lo = a.f; hi = b.f;
}

// ---------------- zero (deg) ----------------
__global__ void zero_kernel(float4* __restrict__ p, int n4) {
    int i = blockIdx.x * blockDim.x + threadIdx.x;
    float4 z = make_float4(0.f, 0.f, 0.f, 0.f);
    for (; i < n4; i += gridDim.x * blockDim.x) p[i] = z;
}

// ---------------- CSR build ----------------
__global__ void hist_kernel(const int* __restrict__ ei, int* __restrict__ deg) {
    int e = blockIdx.x * 256 + threadIdx.x;     // NE = 3125*256 exactly
    atomicAdd(&deg[ei[e]], 1);
}

__global__ void scan1_kernel(const int* __restrict__ deg,
                             int* __restrict__ part, int* __restrict__ bsum) {
    __shared__ int s[256];
    const int tid = threadIdx.x;
    const int i = blockIdx.x * 256 + tid;
    int v = (i < NND) ? deg[i] : 0;
    s[tid] = v;
    __syncthreads();
    #pragma unroll
    for (int off = 1; off < 256; off <<= 1) {
        int t = (tid >= off) ? s[tid - off] : 0;
        __syncthreads();
        s[tid] += t;
        __syncthreads();
    }
    part[i] = s[tid] - v;                        // exclusive
    if (tid == 255) bsum[blockIdx.x] = s[255];
}

__global__ void scan2_kernel(const int* __restrict__ bsum, int* __restrict__ boff) {
    __shared__ int s[256];
    const int tid = threadIdx.x;
    int v = (tid < NB1) ? bsum[tid] : 0;
    s[tid] = v;
    __syncthreads();
    #pragma unroll
    for (int off = 1; off < 256; off <<= 1) {
        int t = (tid >= off) ? s[tid - off] : 0;
        __syncthreads();
        s[tid] += t;
        __syncthreads();
    }
    if (tid < NB1) boff[tid] = s[tid] - v;       // exclusive
}

__global__ void scan3_kernel(const int* __restrict__ part, const int* __restrict__ boff,
                             int* __restrict__ rowptr, int* __restrict__ cursor) {
    int i = blockIdx.x * 256 + threadIdx.x;
    if (i < NND) {
        int v = part[i] + boff[i >> 8];
        rowptr[i] = v;
        cursor[i] = v;
    } else if (i == NND) {
        rowptr[NND] = NE;
    }
}

// scatter packed {col, row, dist2} into CSR order: ONE 16B store per edge
__global__ void scatter_kernel(const int* __restrict__ ei, const float* __restrict__ pos,
                               int* __restrict__ cursor,
                               uint4* __restrict__ epack) {
    int e = blockIdx.x * 256 + threadIdx.x;     // NE exact multiple of 256
    int r = ei[e], c = ei[NE + e];
    float dx = pos[r * 3 + 0] - pos[c * 3 + 0];
    float dy = pos[r * 3 + 1] - pos[c * 3 + 1];
    float dz = pos[r * 3 + 2] - pos[c * 3 + 2];
    float d2 = dx * dx + dy * dy + dz * dz;
    int slot = atomicAdd(&cursor[r], 1);
    uint4 v;
    v.x = (unsigned int)c;
    v.y = (unsigned int)r;
    v.z = __float_as_uint(d2);
    v.w = 0u;
    epack[slot] = v;
}

// ---------------- fused weight swizzle (all 4 matrices + wlf, 1 launch) ----
// Wf flat f = (((ks*4+quad)*128)+n*16+mrow)*8+j  <->  W[k=ks*32+quad*8+j][col=n*16+mrow]
__global__ void wswzall_kernel(const float* __restrict__ W1e, const float* __restrict__ W1n,
                               const float* __restrict__ W2e, const float* __restrict__ W2n,
                               unsigned short* __restrict__ w1f, unsigned short* __restrict__ w1nf,
                               unsigned short* __restrict__ w2f, unsigned short* __restrict__ w2nf,
                               unsigned short* __restrict__ wlf) {
    const int b = blockIdx.x;
    const float* W; unsigned short* Wf; int lb;
    if (b < 128)      { W = W1e; Wf = w1f;  lb = b; }
    else if (b < 256) { W = W1n; Wf = w1nf; lb = b - 128; }
    else if (b < 320) { W = W2e; Wf = w2f;  lb = b - 256; }
    else if (b < 384) { W = W2n; Wf = w2nf; lb = b - 320; }
    else {
        if (threadIdx.x < 128) wlf[threadIdx.x] = f2bf(W1e[256 * D + threadIdx.x]);
        return;
    }
    int f = lb * 256 + threadIdx.x;
    int j    = f & 7;
    int mrow = (f >> 3) & 15;
    int n    = (f >> 7) & 7;
    int rest = f >> 10;
    int quad = rest & 3;
    int ks   = rest >> 2;
    int col = n * 16 + mrow;
    int k   = ks * 32 + quad * 8 + j;
    Wf[f] = f2bf(W[k * D + col]);
}

// ---------------- A' = bf16(x@W1e_top + b1e), B = bf16(x@W1e_bot)  [MFMA] ----
// reads x f32 directly, converts A-frags inline (no separate xbf pass)
__global__ __launch_bounds__(256) void precompute_kernel(
        const float* __restrict__ x,
        const unsigned short* __restrict__ w1f,   // 256x128 swizzled
        const float* __restrict__ b1e,
        unsigned short* __restrict__ A,
        unsigned short* __restrict__ Bm) {
    const int t    = threadIdx.x;
    const int wv   = t >> 6;
    const int lane = t & 63;
    const int mrow = lane & 15;
    const int quad = lane >> 4;
    const int tile = blockIdx.x * 4 + wv;
    if (tile >= 3125) return;
    const int n0 = tile * 16;

    const float4* xrow = (const float4*)(x + ((size_t)(n0 + mrow) << 7));
    const uint4* wp   = (const uint4*)w1f;

    floatx4 accA[8], accB[8];
    #pragma unroll
    for (int n = 0; n < 8; ++n) {
        accA[n] = (floatx4){0.f, 0.f, 0.f, 0.f};
        accB[n] = (floatx4){0.f, 0.f, 0.f, 0.f};
    }

    #pragma unroll
    for (int s = 0; s < 4; ++s) {
        float4 xa = xrow[(s * 4 + quad) * 2 + 0];
        float4 xb = xrow[(s * 4 + quad) * 2 + 1];
        union { shortx8 v; __hip_bfloat162 p[4]; } af;
        af.p[0] = __float22bfloat162_rn(float2{xa.x, xa.y});
        af.p[1] = __float22bfloat162_rn(float2{xa.z, xa.w});
        af.p[2] = __float22bfloat162_rn(float2{xb.x, xb.y});
        af.p[3] = __float22bfloat162_rn(float2{xb.z, xb.w});
        const int baseA = (s * 4 + quad) * 128 + mrow;
        const int baseB = ((s + 4) * 4 + quad) * 128 + mrow;
        #pragma unroll
        for (int n = 0; n < 8; ++n) {
            union { uint4 u; shortx8 v; } bfA, bfB;
            bfA.u = wp[baseA + n * 16];
            bfB.u = wp[baseB + n * 16];
            accA[n] = __builtin_amdgcn_mfma_f32_16x16x32_bf16(af.v, bfA.v, accA[n], 0, 0, 0);
            accB[n] = __builtin_amdgcn_mfma_f32_16x16x32_bf16(af.v, bfB.v, accB[n], 0, 0, 0);
        }
    }

    float bb[8];
    #pragma unroll
    for (int n = 0; n < 8; ++n) bb[n] = b1e[n * 16 + mrow];

    #pragma unroll
    for (int reg = 0; reg < 4; ++reg) {
        const int node = n0 + quad * 4 + reg;
        #pragma unroll
        for (int n = 0; n < 8; ++n) {
            const int col = n * 16 + mrow;
            A[(size_t)node * D + col]  = f2bf(accA[n][reg] + bb[n]);
            Bm[(size_t)node * D + col] = f2bf(accB[n][reg]);
        }
    }
}

// ---------------- E: edge MLP + in-register run reduction -------------------
// Wave = 16 CSR-consecutive edges (50000 tiles). After the epilogue silu each
// lane holds C[row=quad*4+reg][col=k*16+mrow] for its tile. The node-run
// structure of the 16 rows is WAVE-UNIFORM (ballot of r!=r_prev -> 16-bit
// mask), so runs are reduced in registers: 4 predicated adds + 2 shfl_xor
// per col per run (mean ~2 runs/tile). head run -> hp[tile], tail -> tp[tile],
// interior complete nodes -> aggf FINAL. No ef materialization (kills 200MB
// write + 205MB re-read + the aggsum pass; R5-R9 showed edgemlp pinned at
// ~3TB/s fabric regardless of occupancy/VALU -> bytes are the only lever).
__global__ __launch_bounds__(256, 2) void edgered_kernel(
        const unsigned short* __restrict__ Abf,
        const unsigned short* __restrict__ Bbf,
        const uint4* __restrict__ epack,
        const unsigned short* __restrict__ wlf,
        const unsigned short* __restrict__ W2f,
        const float* __restrict__ b2e,
        float* __restrict__ hp,
        float* __restrict__ tp,
        float* __restrict__ aggf) {
    const int t    = threadIdx.x;
    const int wv   = t >> 6;
    const int lane = t & 63;
    const int mrow = lane & 15;
    const int quad = lane >> 4;
    const int tile = blockIdx.x * 4 + wv;       // 12500 * 4 = 50000 exact
    const int e0   = tile * 16;
    const int eme  = e0 + mrow;                 // this lane's A-frag edge

    const uint4 ep = epack[eme];                // single coalesced 16B gather
    const int   c  = (int)ep.x;
    const int   r  = (int)ep.y;                 // CSR-sorted -> L1 broadcast
    const float d2 = __uint_as_float(ep.z);

    const uint4* arow = (const uint4*)(Abf + ((size_t)r << 7));
    const uint4* brow = (const uint4*)(Bbf + ((size_t)c << 7));
    const uint4* wlq  = (const uint4*)wlf;
    const uint4* w2p  = (const uint4*)W2f;

    // hoisted loads: 12 scattered loads in flight before compute
    uint4 au[4], bu[4], wu[4];
    #pragma unroll
    for (int s = 0; s < 4; ++s) {
        au[s] = arow[s * 4 + quad];
        bu[s] = brow[s * 4 + quad];
        wu[s] = wlq[s * 4 + quad];
    }

    floatx4 acc[8];
    #pragma unroll
    for (int k = 0; k < 8; ++k) acc[k] = (floatx4){0.f, 0.f, 0.f, 0.f};

    #pragma unroll
    for (int s = 0; s < 4; ++s) {
        float a0, a1, a2, a3, a4, a5, a6, a7;
        float q0, q1, q2, q3, q4, q5, q6, q7;
        float w0, w1, w2, w3, w4, w5, w6, w7;
        unpk(au[s].x, a0, a1); unpk(au[s].y, a2, a3);
        unpk(au[s].z, a4, a5); unpk(au[s].w, a6, a7);
        unpk(bu[s].x, q0, q1); unpk(bu[s].y, q2, q3);
        unpk(bu[s].z, q4, q5); unpk(bu[s].w, q6, q7);
        unpk(wu[s].x, w0, w1); unpk(wu[s].y, w2, w3);
        unpk(wu[s].z, w4, w5); unpk(wu[s].w, w6, w7);

        float h0 = silu_f(fmaf(d2, w0, a0 + q0));
        float h1 = silu_f(fmaf(d2, w1, a1 + q1));
        float h2 = silu_f(fmaf(d2, w2, a2 + q2));
        float h3 = silu_f(fmaf(d2, w3, a3 + q3));
        float h4 = silu_f(fmaf(d2, w4, a4 + q4));
        float h5 = silu_f(fmaf(d2, w5, a5 + q5));
        float h6 = silu_f(fmaf(d2, w6, a6 + q6));
        float h7 = silu_f(fmaf(d2, w7, a7 + q7));

        union { shortx8 v; __hip_bfloat162 p[4]; } af;
        af.p[0] = __float22bfloat162_rn(float2{h0, h1});
        af.p[1] = __float22bfloat162_rn(float2{h2, h3});
        af.p[2] = __float22bfloat162_rn(float2{h4, h5});
        af.p[3] = __float22bfloat162_rn(float2{h6, h7});

        const int base = (s * 4 + quad) * 128 + mrow;
        #pragma unroll
        for (int k = 0; k < 8; ++k) {
            union { uint4 u; shortx8 v; } bf;
            bf.u = w2p[base + k * 16];
            acc[k] = __builtin_amdgcn_mfma_f32_16x16x32_bf16(af.v, bf.v, acc[k], 0, 0, 0);
        }
    }

    float bias[8];
    #pragma unroll
    for (int k = 0; k < 8; ++k) bias[k] = b2e[k * 16 + mrow];

    // second-layer silu in place
    #pragma unroll
    for (int k = 0; k < 8; ++k) {
        #pragma unroll
        for (int reg = 0; reg < 4; ++reg)
            acc[k][reg] = silu_f(acc[k][reg] + bias[k]);
    }

    // wave-uniform run mask over the 16 rows (r depends only on mrow)
    const int rp = __shfl(r, (mrow - 1) & 15);   // r of previous row
    const bool newrun = (mrow == 0) || (r != rp);
    const unsigned mask16 = (unsigned)(__ballot(newrun) & 0xffffull);

    int i = 0;
    while (i < 16) {
        const unsigned rest = mask16 & ~((1u << (i + 1)) - 1u);
        const int j = rest ? (int)__builtin_ctz(rest) : 16;  // run = rows [i,j)
        const int n = __shfl(r, i);                          // node of this run
        float s[8];
        #pragma unroll
        for (int k = 0; k < 8; ++k) {
            float v = 0.f;
            #pragma unroll
            for (int reg = 0; reg < 4; ++reg) {
                const int row = quad * 4 + reg;
                v += (row >= i && row < j) ? acc[k][reg] : 0.f;
            }
            v += __shfl_xor(v, 16);
            v += __shfl_xor(v, 32);
            s[k] = v;
        }
        if (quad == 0) {
            float* dst;
            if (i == 0)       dst = hp + (size_t)tile * 128;      // head run
            else if (j == 16) dst = tp + (size_t)tile * 128;      // tail run
            else              dst = aggf + (size_t)n * 128;       // complete
            #pragma unroll
            for (int k = 0; k < 8; ++k) dst[k * 16 + mrow] = s[k];
        }
        i = j;
    }
}

// ---------------- combine: stitch boundary nodes from hp/tp ----------------
// Wave per node, float2 per lane. Interior single-tile runs were written
// final by edgered (skip). hp[t] = run containing row 0 of tile t (covers
// whole tile when one node spans it); tp[t] written iff tail run distinct,
// which is exactly when a path below reads it (CSR-sorted rows).
__global__ __launch_bounds__(256) void combine_kernel(
        const float* __restrict__ hp,
        const float* __restrict__ tp,
        const int* __restrict__ rowptr,
        float* __restrict__ aggf) {
    const int lane = threadIdx.x & 63;
    const int node = blockIdx.x * 4 + (threadIdx.x >> 6);  // 12500*4 = 50000
    const int start = rowptr[node];
    const int end   = rowptr[node + 1];
    float2* ag2 = (float2*)(aggf + ((size_t)node << 7));
    const float2* h2 = (const float2*)hp;
    const float2* t2 = (const float2*)tp;

    if (start == end) { ag2[lane] = make_float2(0.f, 0.f); return; }
    const int t0 = start >> 4, t1 = (end - 1) >> 4;
    if (t0 == t1) {
        if ((start & 15) == 0)    ag2[lane] = h2[(size_t)t0 * 64 + lane];
        else if ((end & 15) == 0) ag2[lane] = t2[(size_t)t0 * 64 + lane];
        // else: interior run, already final in aggf
        return;
    }
    float2 a = ((start & 15) == 0) ? h2[(size_t)t0 * 64 + lane]
                                   : t2[(size_t)t0 * 64 + lane];
    for (int tt = t0 + 1; tt <= t1; ++tt) {      // middles + t1 are head runs
        float2 b = h2[(size_t)tt * 64 + lane];
        a.x += b.x; a.y += b.y;
    }
    ag2[lane] = a;
}

// ---------------- node MLP + residual + LayerNorm  [MFMA] ----------------
// 1 wave per block, block = 16 nodes. Stage1 K=256 ([x|agg] bf16, converted
// inline from f32), transpose via LDS (304 B pitch), stage2 K=128, epilogue
// residual + LN via quad shfl.
__global__ __launch_bounds__(64) void node_kernel(
        const float* __restrict__ aggf,
        const unsigned short* __restrict__ w1nf,  // 256x128 swizzled
        const float* __restrict__ b1n,
        const unsigned short* __restrict__ w2nf,  // 128x128 swizzled
        const float* __restrict__ b2n,
        const float* __restrict__ x,
        const float* __restrict__ gamma,
        const float* __restrict__ beta,
        float* __restrict__ out) {
    __shared__ __align__(16) unsigned short ts[16 * TPITCH];
    const int lane = threadIdx.x;
    const int mrow = lane & 15;
    const int quad = lane >> 4;
    const int n0 = blockIdx.x * 16;      // 3125 blocks exact

    const float4* xrow  = (const float4*)(x + ((size_t)(n0 + mrow) << 7));
    const float4* growf = (const float4*)(aggf + ((size_t)(n0 + mrow) << 7));
    const uint4*  w1p   = (const uint4*)w1nf;
    const uint4*  w2p   = (const uint4*)w2nf;

    floatx4 acc[8];
    #pragma unroll
    for (int n = 0; n < 8; ++n) {
        float b = b1n[n * 16 + mrow];
        acc[n] = (floatx4){b, b, b, b};
    }

    #pragma unroll
    for (int s = 0; s < 4; ++s) {
        float4 xa = xrow[(s * 4 + quad) * 2 + 0];
        float4 xb = xrow[(s * 4 + quad) * 2 + 1];
        union { shortx8 v; __hip_bfloat162 p[4]; } af;
        af.p[0] = __float22bfloat162_rn(float2{xa.x, xa.y});
        af.p[1] = __float22bfloat162_rn(float2{xa.z, xa.w});
        af.p[2] = __float22bfloat162_rn(float2{xb.x, xb.y});
        af.p[3] = __float22bfloat162_rn(float2{xb.z, xb.w});
        const int base = (s * 4 + quad) * 128 + mrow;
        #pragma unroll
        for (int n = 0; n < 8; ++n) {
            union { uint4 u; shortx8 v; } bf;
            bf.u = w1p[base + n * 16];
            acc[n] = __builtin_amdgcn_mfma_f32_16x16x32_bf16(af.v, bf.v, acc[n], 0, 0, 0);
        }
    }
    #pragma unroll
    for (int s = 0; s < 4; ++s) {
        float4 g0 = growf[(s * 4 + quad) * 2 + 0];
        float4 g1 = growf[(s * 4 + quad) * 2 + 1];
        union { shortx8 v; __hip_bfloat162 p[4]; } af;
        af.p[0] = __float22bfloat162_rn(float2{g0.x, g0.y});
        af.p[1] = __float22bfloat162_rn(float2{g0.z, g0.w});
        af.p[2] = __float22bfloat162_rn(float2{g1.x, g1.y});
        af.p[3] = __float22bfloat162_rn(float2{g1.z, g1.w});
        const int base = ((s + 4) * 4 + quad) * 128 + mrow;
        #pragma unroll
        for (int n = 0; n < 8; ++n) {
            union { uint4 u; shortx8 v; } bf;
            bf.u = w1p[base + n * 16];
            acc[n] = __builtin_amdgcn_mfma_f32_16x16x32_bf16(af.v, bf.v, acc[n], 0, 0, 0);
        }
    }

    // silu -> LDS (row-major [m][col], transpose for stage-2 A-frags)
    #pragma unroll
    for (int reg = 0; reg < 4; ++reg) {
        const int m = quad * 4 + reg;
        #pragma unroll
        for (int n = 0; n < 8; ++n)
            ts[m * TPITCH + n * 16 + mrow] = f2bf(silu_f(acc[n][reg]));
    }
    __syncthreads();   // single wave: cheap; guarantees LDS RAW ordering

    floatx4 acc2[8];
    #pragma unroll
    for (int n = 0; n < 8; ++n) {
        float b = b2n[n * 16 + mrow];
        acc2[n] = (floatx4){b, b, b, b};
    }
    #pragma unroll
    for (int s = 0; s < 4; ++s) {
        shortx8 af2 = *(const shortx8*)((const char*)ts +
                        mrow * (TPITCH * 2) + (s * 4 + quad) * 16);
        const int base = (s * 4 + quad) * 128 + mrow;
        #pragma unroll
        for (int n = 0; n < 8; ++n) {
            union { uint4 u; shortx8 v; } bf;
            bf.u = w2p[base + n * 16];
            acc2[n] = __builtin_amdgcn_mfma_f32_16x16x32_bf16(af2, bf.v, acc2[n], 0, 0, 0);
        }
    }

    // epilogue: residual + LayerNorm (reduce over the 16 lanes of each quad)
    float g[8], bt[8];
    #pragma unroll
    for (int n = 0; n < 8; ++n) {
        g[n]  = gamma[n * 16 + mrow];
        bt[n] = beta[n * 16 + mrow];
    }
    #pragma unroll
    for (int reg = 0; reg < 4; ++reg) {
        const int node = n0 + quad * 4 + reg;
        float u[8];
        float s1 = 0.f, s2 = 0.f;
        #pragma unroll
        for (int n = 0; n < 8; ++n) {
            u[n] = acc2[n][reg] + x[(size_t)node * D + n * 16 + mrow];
            s1 += u[n];
            s2 += u[n] * u[n];
        }
        #pragma unroll
        for (int off = 1; off < 16; off <<= 1) {
            s1 += __shfl_xor(s1, off);
            s2 += __shfl_xor(s2, off);
        }
        const float mu  = s1 * (1.f / 128.f);
        const float var = s2 * (1.f / 128.f) - mu * mu;
        const float rs  = rsqrtf(var + 1e-5f);
        #pragma unroll
        for (int n = 0; n < 8; ++n)
            out[(size_t)node * D + n * 16 + mrow] = (u[n] - mu) * rs * g[n] + bt[n];
    }
}

extern "C" void kernel_launch(void* const* d_in, const int* in_sizes, int n_in,
                              void* d_out, int out_size, void* d_ws, size_t ws_size,
                              hipStream_t stream) {
    const float* x     = (const float*)d_in[0];
    const float* pos   = (const float*)d_in[1];
    const int*   ei    = (const int*)d_in[2];
    const float* W1e   = (const float*)d_in[3];
    const float* b1e   = (const float*)d_in[4];
    const float* W2e   = (const float*)d_in[5];
    const float* b2e   = (const float*)d_in[6];
    const float* W1n   = (const float*)d_in[7];
    const float* b1n   = (const float*)d_in[8];
    const float* W2n   = (const float*)d_in[9];
    const float* b2n   = (const float*)d_in[10];
    const float* gamma = (const float*)d_in[11];
    const float* beta  = (const float*)d_in[12];
    float* out = (float*)d_out;

    // ws layout — total footprint ~116 MB (no ef buffer; no fallback needed).
    int*            deg    = (int*)d_ws;                              // 50176
    int*            part   = deg + 50176;
    int*            bsum   = part + 50176;
    int*            boff   = bsum + 256;
    int*            rowptr = boff + 256;                              // 50004
    int*            cursor = rowptr + 50004;                          // 50000
    // 200868 ints = 803472 B, divisible by 16 -> epack aligned
    uint4*          epack  = (uint4*)(cursor + 50000);                // 12.8 MB
    unsigned short* Abf    = (unsigned short*)(epack + NE);           // 12.8 MB
    unsigned short* Bbf    = Abf + (size_t)NND * D;                   // 12.8 MB
    unsigned short* w1f    = Bbf + (size_t)NND * D;                   // 64 KB (256x128)
    unsigned short* w1nf   = w1f + 256 * D;                           // 64 KB (256x128)
    unsigned short* w2f    = w1nf + 256 * D;                          // 32 KB (128x128)
    unsigned short* w2nf   = w2f + D * D;                             // 32 KB (128x128)
    unsigned short* wlf    = w2nf + D * D;                            // 256 B
    float*          aggf   = (float*)(wlf + 128);                     // 25.6 MB
    float*          hp     = aggf + (size_t)NND * D;                  // 25.6 MB (50000x128)
    float*          tp     = hp + (size_t)(NE / 16) * D;              // 25.6 MB

    // zero deg only
    zero_kernel<<<49, 256, 0, stream>>>((float4*)deg, 50176 / 4);

    // CSR build
    hist_kernel<<<NE / 256, 256, 0, stream>>>(ei, deg);
    scan1_kernel<<<NB1, 256, 0, stream>>>(deg, part, bsum);
    scan2_kernel<<<1, 256, 0, stream>>>(bsum, boff);
    scan3_kernel<<<197, 256, 0, stream>>>(part, boff, rowptr, cursor);
    scatter_kernel<<<NE / 256, 256, 0, stream>>>(ei, pos, cursor, epack);

    // fused weight swizzles (1 launch)
    wswzall_kernel<<<385, 256, 0, stream>>>(W1e, W1n, W2e, W2n,
                                            w1f, w1nf, w2f, w2nf, wlf);

    // A'/B precompute (MFMA, reads x f32 directly)
    precompute_kernel<<<782, 256, 0, stream>>>(x, w1f, b1e, Abf, Bbf);

    // edge MLP + in-register run reduction (interior nodes final)
    edgered_kernel<<<NE / 64, 256, 0, stream>>>(Abf, Bbf, epack, wlf, w2f, b2e,
                                                hp, tp, aggf);
    // stitch boundary nodes (+ zero deg-0 nodes)
    combine_kernel<<<NND / 4, 256, 0, stream>>>(hp, tp, rowptr, aggf);

    // node MLP + residual + LN (MFMA)
    node_kernel<<<NND / 16, 64, 0, stream>>>(aggf, w1nf, b1n, w2nf, b2n,
                                             x, gamma, beta, out);
}

// Round 11
// 343.956 us; speedup vs baseline: 1.1643x; 1.0100x over previous
//
#include <hip/hip_runtime.h>
#include <hip/hip_bf16.h>
#include <math.h>

#define D 128
#define NND 50000
#define NE 800000
#define NB1 196        // scan blocks: 196*256 = 50176 >= 50000
#define TPITCH 152     // ushort pitch for node transpose tile (304 B = 19*16)

typedef __attribute__((ext_vector_type(8))) short shortx8;
typedef __attribute__((ext_vector_type(4))) float floatx4;

__device__ __forceinline__ float silu_f(float v) {
    // v / (1+e^-v) with hardware rcp (1 ulp) instead of IEEE divide
    return v * __builtin_amdgcn_rcpf(1.0f + __expf(-v));
}
__device__ __forceinline__ unsigned short f2bf(float f) {
    union { float f; unsigned int u; } v; v.f = f;
    unsigned int u = v.u;
    u += 0x7fffu + ((u >> 16) & 1u);   // RNE
    return (unsigned short)(u >> 16);
}
__device__ __forceinline__ void unpk(unsigned int u, float& lo, float& hi) {
    union { unsigned int x; float f; } a, b;
    a.x = u << 16;
    b.x = u & 0xffff0000u;
    lo = a.f; hi = b.f;
}

// ---------------- zero (deg) ----------------
__global__ void zero_kernel(float4* __restrict__ p, int n4) {
    int i = blockIdx.x * blockDim.x + threadIdx.x;
    float4 z = make_float4(0.f, 0.f, 0.f, 0.f);
    for (; i < n4; i += gridDim.x * blockDim.x) p[i] = z;
}

// ---------------- CSR build ----------------
__global__ void hist_kernel(const int* __restrict__ ei, int* __restrict__ deg) {
    int e = blockIdx.x * 256 + threadIdx.x;     // NE = 3125*256 exactly
    atomicAdd(&deg[ei[e]], 1);
}

__global__ void scan1_kernel(const int* __restrict__ deg,
                             int* __restrict__ part, int* __restrict__ bsum) {
    __shared__ int s[256];
    const int tid = threadIdx.x;
    const int i = blockIdx.x * 256 + tid;
    int v = (i < NND) ? deg[i] : 0;
    s[tid] = v;
    __syncthreads();
    #pragma unroll
    for (int off = 1; off < 256; off <<= 1) {
        int t = (tid >= off) ? s[tid - off] : 0;
        __syncthreads();
        s[tid] += t;
        __syncthreads();
    }
    part[i] = s[tid] - v;                        // exclusive
    if (tid == 255) bsum[blockIdx.x] = s[255];
}

__global__ void scan2_kernel(const int* __restrict__ bsum, int* __restrict__ boff) {
    __shared__ int s[256];
    const int tid = threadIdx.x;
    int v = (tid < NB1) ? bsum[tid] : 0;
    s[tid] = v;
    __syncthreads();
    #pragma unroll
    for (int off = 1; off < 256; off <<= 1) {
        int t = (tid >= off) ? s[tid - off] : 0;
        __syncthreads();
        s[tid] += t;
        __syncthreads();
    }
    if (tid < NB1) boff[tid] = s[tid] - v;       // exclusive
}

__global__ void scan3_kernel(const int* __restrict__ part, const int* __restrict__ boff,
                             int* __restrict__ rowptr, int* __restrict__ cursor) {
    int i = blockIdx.x * 256 + threadIdx.x;
    if (i < NND) {
        int v = part[i] + boff[i >> 8];
        rowptr[i] = v;
        cursor[i] = v;
    } else if (i == NND) {
        rowptr[NND] = NE;
    }
}

// scatter packed {col, row, dist2} into CSR order: ONE 16B store per edge
__global__ void scatter_kernel(const int* __restrict__ ei, const float* __restrict__ pos,
                               int* __restrict__ cursor,
                               uint4* __restrict__ epack) {
    int e = blockIdx.x * 256 + threadIdx.x;     // NE exact multiple of 256
    int r = ei[e], c = ei[NE + e];
    float dx = pos[r * 3 + 0] - pos[c * 3 + 0];
    float dy = pos[r * 3 + 1] - pos[c * 3 + 1];
    float dz = pos[r * 3 + 2] - pos[c * 3 + 2];
    float d2 = dx * dx + dy * dy + dz * dz;
    int slot = atomicAdd(&cursor[r], 1);
    uint4 v;
    v.x = (unsigned int)c;
    v.y = (unsigned int)r;
    v.z = __float_as_uint(d2);
    v.w = 0u;
    epack[slot] = v;
}

// ---------------- fused weight swizzle (all 4 matrices + wlf, 1 launch) ----
// Wf flat f = (((ks*4+quad)*128)+n*16+mrow)*8+j  <->  W[k=ks*32+quad*8+j][col=n*16+mrow]
__global__ void wswzall_kernel(const float* __restrict__ W1e, const float* __restrict__ W1n,
                               const float* __restrict__ W2e, const float* __restrict__ W2n,
                               unsigned short* __restrict__ w1f, unsigned short* __restrict__ w1nf,
                               unsigned short* __restrict__ w2f, unsigned short* __restrict__ w2nf,
                               unsigned short* __restrict__ wlf) {
    const int b = blockIdx.x;
    const float* W; unsigned short* Wf; int lb;
    if (b < 128)      { W = W1e; Wf = w1f;  lb = b; }
    else if (b < 256) { W = W1n; Wf = w1nf; lb = b - 128; }
    else if (b < 320) { W = W2e; Wf = w2f;  lb = b - 256; }
    else if (b < 384) { W = W2n; Wf = w2nf; lb = b - 320; }
    else {
        if (threadIdx.x < 128) wlf[threadIdx.x] = f2bf(W1e[256 * D + threadIdx.x]);
        return;
    }
    int f = lb * 256 + threadIdx.x;
    int j    = f & 7;
    int mrow = (f >> 3) & 15;
    int n    = (f >> 7) & 7;
    int rest = f >> 10;
    int quad = rest & 3;
    int ks   = rest >> 2;
    int col = n * 16 + mrow;
    int k   = ks * 32 + quad * 8 + j;
    Wf[f] = f2bf(W[k * D + col]);
}

// ---------------- A' = bf16(x@W1e_top + b1e), B = bf16(x@W1e_bot)  [MFMA] ----
// reads x f32 directly, converts A-frags inline (no separate xbf pass)
__global__ __launch_bounds__(256) void precompute_kernel(
        const float* __restrict__ x,
        const unsigned short* __restrict__ w1f,   // 256x128 swizzled
        const float* __restrict__ b1e,
        unsigned short* __restrict__ A,
        unsigned short* __restrict__ Bm) {
    const int t    = threadIdx.x;
    const int wv   = t >> 6;
    const int lane = t & 63;
    const int mrow = lane & 15;
    const int quad = lane >> 4;
    const int tile = blockIdx.x * 4 + wv;
    if (tile >= 3125) return;
    const int n0 = tile * 16;

    const float4* xrow = (const float4*)(x + ((size_t)(n0 + mrow) << 7));
    const uint4* wp   = (const uint4*)w1f;

    floatx4 accA[8], accB[8];
    #pragma unroll
    for (int n = 0; n < 8; ++n) {
        accA[n] = (floatx4){0.f, 0.f, 0.f, 0.f};
        accB[n] = (floatx4){0.f, 0.f, 0.f, 0.f};
    }

    #pragma unroll
    for (int s = 0; s < 4; ++s) {
        float4 xa = xrow[(s * 4 + quad) * 2 + 0];
        float4 xb = xrow[(s * 4 + quad) * 2 + 1];
        union { shortx8 v; __hip_bfloat162 p[4]; } af;
        af.p[0] = __float22bfloat162_rn(float2{xa.x, xa.y});
        af.p[1] = __float22bfloat162_rn(float2{xa.z, xa.w});
        af.p[2] = __float22bfloat162_rn(float2{xb.x, xb.y});
        af.p[3] = __float22bfloat162_rn(float2{xb.z, xb.w});
        const int baseA = (s * 4 + quad) * 128 + mrow;
        const int baseB = ((s + 4) * 4 + quad) * 128 + mrow;
        #pragma unroll
        for (int n = 0; n < 8; ++n) {
            union { uint4 u; shortx8 v; } bfA, bfB;
            bfA.u = wp[baseA + n * 16];
            bfB.u = wp[baseB + n * 16];
            accA[n] = __builtin_amdgcn_mfma_f32_16x16x32_bf16(af.v, bfA.v, accA[n], 0, 0, 0);
            accB[n] = __builtin_amdgcn_mfma_f32_16x16x32_bf16(af.v, bfB.v, accB[n], 0, 0, 0);
        }
    }

    float bb[8];
    #pragma unroll
    for (int n = 0; n < 8; ++n) bb[n] = b1e[n * 16 + mrow];

    #pragma unroll
    for (int reg = 0; reg < 4; ++reg) {
        const int node = n0 + quad * 4 + reg;
        #pragma unroll
        for (int n = 0; n < 8; ++n) {
            const int col = n * 16 + mrow;
            A[(size_t)node * D + col]  = f2bf(accA[n][reg] + bb[n]);
            Bm[(size_t)node * D + col] = f2bf(accB[n][reg]);
        }
    }
}

// ---------------- E: edge MLP + in-register run reduction -------------------
// Wave = 16 CSR-consecutive edges (50000 tiles). After the epilogue silu each
// lane holds C[row=quad*4+reg][col=k*16+mrow] for its tile. The node-run
// structure of the 16 rows is WAVE-UNIFORM (ballot of r!=r_prev -> 16-bit
// mask), so runs are reduced in registers: 4 predicated adds + 2 shfl_xor
// per col per run (mean ~2 runs/tile). head run -> hp[tile], tail -> tp[tile],
// interior complete nodes -> aggf FINAL.
__global__ __launch_bounds__(256, 2) void edgered_kernel(
        const unsigned short* __restrict__ Abf,
        const unsigned short* __restrict__ Bbf,
        const uint4* __restrict__ epack,
        const unsigned short* __restrict__ wlf,
        const unsigned short* __restrict__ W2f,
        const float* __restrict__ b2e,
        float* __restrict__ hp,
        float* __restrict__ tp,
        float* __restrict__ aggf) {
    const int t    = threadIdx.x;
    const int wv   = t >> 6;
    const int lane = t & 63;
    const int mrow = lane & 15;
    const int quad = lane >> 4;
    const int tile = blockIdx.x * 4 + wv;       // 12500 * 4 = 50000 exact
    const int e0   = tile * 16;
    const int eme  = e0 + mrow;                 // this lane's A-frag edge

    const uint4 ep = epack[eme];                // single coalesced 16B gather
    const int   c  = (int)ep.x;
    const int   r  = (int)ep.y;                 // CSR-sorted -> L1 broadcast
    const float d2 = __uint_as_float(ep.z);

    const uint4* arow = (const uint4*)(Abf + ((size_t)r << 7));
    const uint4* brow = (const uint4*)(Bbf + ((size_t)c << 7));
    const uint4* wlq  = (const uint4*)wlf;
    const uint4* w2p  = (const uint4*)W2f;

    // hoisted loads: 12 scattered loads in flight before compute
    uint4 au[4], bu[4], wu[4];
    #pragma unroll
    for (int s = 0; s < 4; ++s) {
        au[s] = arow[s * 4 + quad];
        bu[s] = brow[s * 4 + quad];
        wu[s] = wlq[s * 4 + quad];
    }

    floatx4 acc[8];
    #pragma unroll
    for (int k = 0; k < 8; ++k) acc[k] = (floatx4){0.f, 0.f, 0.f, 0.f};

    #pragma unroll
    for (int s = 0; s < 4; ++s) {
        float a0, a1, a2, a3, a4, a5, a6, a7;
        float q0, q1, q2, q3, q4, q5, q6, q7;
        float w0, w1, w2, w3, w4, w5, w6, w7;
        unpk(au[s].x, a0, a1); unpk(au[s].y, a2, a3);
        unpk(au[s].z, a4, a5); unpk(au[s].w, a6, a7);
        unpk(bu[s].x, q0, q1); unpk(bu[s].y, q2, q3);
        unpk(bu[s].z, q4, q5); unpk(bu[s].w, q6, q7);
        unpk(wu[s].x, w0, w1); unpk(wu[s].y, w2, w3);
        unpk(wu[s].z, w4, w5); unpk(wu[s].w, w6, w7);

        float h0 = silu_f(fmaf(d2, w0, a0 + q0));
        float h1 = silu_f(fmaf(d2, w1, a1 + q1));
        float h2 = silu_f(fmaf(d2, w2, a2 + q2));
        float h3 = silu_f(fmaf(d2, w3, a3 + q3));
        float h4 = silu_f(fmaf(d2, w4, a4 + q4));
        float h5 = silu_f(fmaf(d2, w5, a5 + q5));
        float h6 = silu_f(fmaf(d2, w6, a6 + q6));
        float h7 = silu_f(fmaf(d2, w7, a7 + q7));

        union { shortx8 v; __hip_bfloat162 p[4]; } af;
        af.p[0] = __float22bfloat162_rn(float2{h0, h1});
        af.p[1] = __float22bfloat162_rn(float2{h2, h3});
        af.p[2] = __float22bfloat162_rn(float2{h4, h5});
        af.p[3] = __float22bfloat162_rn(float2{h6, h7});

        const int base = (s * 4 + quad) * 128 + mrow;
        #pragma unroll
        for (int k = 0; k < 8; ++k) {
            union { uint4 u; shortx8 v; } bf;
            bf.u = w2p[base + k * 16];
            acc[k] = __builtin_amdgcn_mfma_f32_16x16x32_bf16(af.v, bf.v, acc[k], 0, 0, 0);
        }
    }

    float bias[8];
    #pragma unroll
    for (int k = 0; k < 8; ++k) bias[k] = b2e[k * 16 + mrow];

    // second-layer silu in place
    #pragma unroll
    for (int k = 0; k < 8; ++k) {
        #pragma unroll
        for (int reg = 0; reg < 4; ++reg)
            acc[k][reg] = silu_f(acc[k][reg] + bias[k]);
    }

    // wave-uniform run mask over the 16 rows (r depends only on mrow)
    const int rp = __shfl(r, (mrow - 1) & 15);   // r of previous row
    const bool newrun = (mrow == 0) || (r != rp);
    const unsigned mask16 = (unsigned)(__ballot(newrun) & 0xffffull);

    int i = 0;
    while (i < 16) {
        const unsigned rest = mask16 & ~((1u << (i + 1)) - 1u);
        const int j = rest ? (int)__builtin_ctz(rest) : 16;  // run = rows [i,j)
        const int n = __shfl(r, i);                          // node of this run
        float s[8];
        #pragma unroll
        for (int k = 0; k < 8; ++k) {
            float v = 0.f;
            #pragma unroll
            for (int reg = 0; reg < 4; ++reg) {
                const int row = quad * 4 + reg;
                v += (row >= i && row < j) ? acc[k][reg] : 0.f;
            }
            v += __shfl_xor(v, 16);
            v += __shfl_xor(v, 32);
            s[k] = v;
        }
        if (quad == 0) {
            float* dst;
            if (i == 0)       dst = hp + (size_t)tile * 128;      // head run
            else if (j == 16) dst = tp + (size_t)tile * 128;      // tail run
            else              dst = aggf + (size_t)n * 128;       // complete
            #pragma unroll
            for (int k = 0; k < 8; ++k) dst[k * 16 + mrow] = s[k];
        }
        i = j;
    }
}

// ---------------- node MLP + residual + LayerNorm  [MFMA] ----------------
// 1 wave per block, block = 16 nodes. The boundary-node stitch (formerly
// combine_kernel) is FUSED: each lane (mrow) classifies its node from rowptr
// and sources agg chunks directly from hp/tp/aggf (mean ~2 tiles/node).
// Convention (proven in R10's combine): hp[t] = run containing row 0 of tile
// t; tp[t] valid iff tail run distinct, which is exactly when read.
__global__ __launch_bounds__(64) void node_kernel(
        const float* __restrict__ aggf,
        const float* __restrict__ hp,
        const float* __restrict__ tp,
        const int* __restrict__ rowptr,
        const unsigned short* __restrict__ w1nf,  // 256x128 swizzled
        const float* __restrict__ b1n,
        const unsigned short* __restrict__ w2nf,  // 128x128 swizzled
        const float* __restrict__ b2n,
        const float* __restrict__ x,
        const float* __restrict__ gamma,
        const float* __restrict__ beta,
        float* __restrict__ out) {
    __shared__ __align__(16) unsigned short ts[16 * TPITCH];
    const int lane = threadIdx.x;
    const int mrow = lane & 15;
    const int quad = lane >> 4;
    const int n0 = blockIdx.x * 16;      // 3125 blocks exact

    const float4* xrow = (const float4*)(x + ((size_t)(n0 + mrow) << 7));
    const uint4*  w1p  = (const uint4*)w1nf;
    const uint4*  w2p  = (const uint4*)w2nf;

    // classify this lane's node for the agg stitch
    const int nd = n0 + mrow;
    const int st = rowptr[nd];
    const int en = rowptr[nd + 1];
    int mode;                       // 0=empty, 1=single src, 2=multi-tile
    int t0 = 0, t1 = 0;
    const float4* gsrc = (const float4*)(aggf + ((size_t)nd << 7));
    if (st == en) {
        mode = 0;
    } else {
        t0 = st >> 4; t1 = (en - 1) >> 4;
        if (t0 == t1) {
            mode = 1;
            if ((st & 15) == 0)      gsrc = (const float4*)(hp + (size_t)t0 * 128);
            else if ((en & 15) == 0) gsrc = (const float4*)(tp + (size_t)t0 * 128);
            // else: interior run already final in aggf (gsrc default)
        } else {
            mode = 2;
        }
    }
    const float4* fsrc = ((st & 15) == 0) ? (const float4*)(hp + (size_t)t0 * 128)
                                          : (const float4*)(tp + (size_t)t0 * 128);

    floatx4 acc[8];
    #pragma unroll
    for (int n = 0; n < 8; ++n) {
        float b = b1n[n * 16 + mrow];
        acc[n] = (floatx4){b, b, b, b};
    }

    #pragma unroll
    for (int s = 0; s < 4; ++s) {
        float4 xa = xrow[(s * 4 + quad) * 2 + 0];
        float4 xb = xrow[(s * 4 + quad) * 2 + 1];
        union { shortx8 v; __hip_bfloat162 p[4]; } af;
        af.p[0] = __float22bfloat162_rn(float2{xa.x, xa.y});
        af.p[1] = __float22bfloat162_rn(float2{xa.z, xa.w});
        af.p[2] = __float22bfloat162_rn(float2{xb.x, xb.y});
        af.p[3] = __float22bfloat162_rn(float2{xb.z, xb.w});
        const int base = (s * 4 + quad) * 128 + mrow;
        #pragma unroll
        for (int n = 0; n < 8; ++n) {
            union { uint4 u; shortx8 v; } bf;
            bf.u = w1p[base + n * 16];
            acc[n] = __builtin_amdgcn_mfma_f32_16x16x32_bf16(af.v, bf.v, acc[n], 0, 0, 0);
        }
    }
    #pragma unroll
    for (int s = 0; s < 4; ++s) {
        const int ch = (s * 4 + quad) * 2;
        float4 g0, g1;
        if (mode == 0) {
            g0 = make_float4(0.f, 0.f, 0.f, 0.f);
            g1 = g0;
        } else if (mode == 1) {
            g0 = gsrc[ch + 0];
            g1 = gsrc[ch + 1];
        } else {
            g0 = fsrc[ch + 0];
            g1 = fsrc[ch + 1];
            for (int tt = t0 + 1; tt <= t1; ++tt) {  // middles + t1 = head runs
                const float4* hs = (const float4*)(hp + (size_t)tt * 128);
                float4 a = hs[ch + 0], b = hs[ch + 1];
                g0.x += a.x; g0.y += a.y; g0.z += a.z; g0.w += a.w;
                g1.x += b.x; g1.y += b.y; g1.z += b.z; g1.w += b.w;
            }
        }
        union { shortx8 v; __hip_bfloat162 p[4]; } af;
        af.p[0] = __float22bfloat162_rn(float2{g0.x, g0.y});
        af.p[1] = __float22bfloat162_rn(float2{g0.z, g0.w});
        af.p[2] = __float22bfloat162_rn(float2{g1.x, g1.y});
        af.p[3] = __float22bfloat162_rn(float2{g1.z, g1.w});
        const int base = ((s + 4) * 4 + quad) * 128 + mrow;
        #pragma unroll
        for (int n = 0; n < 8; ++n) {
            union { uint4 u; shortx8 v; } bf;
            bf.u = w1p[base + n * 16];
            acc[n] = __builtin_amdgcn_mfma_f32_16x16x32_bf16(af.v, bf.v, acc[n], 0, 0, 0);
        }
    }

    // silu -> LDS (row-major [m][col], transpose for stage-2 A-frags)
    #pragma unroll
    for (int reg = 0; reg < 4; ++reg) {
        const int m = quad * 4 + reg;
        #pragma unroll
        for (int n = 0; n < 8; ++n)
            ts[m * TPITCH + n * 16 + mrow] = f2bf(silu_f(acc[n][reg]));
    }
    __syncthreads();   // single wave: cheap; guarantees LDS RAW ordering

    floatx4 acc2[8];
    #pragma unroll
    for (int n = 0; n < 8; ++n) {
        float b = b2n[n * 16 + mrow];
        acc2[n] = (floatx4){b, b, b, b};
    }
    #pragma unroll
    for (int s = 0; s < 4; ++s) {
        shortx8 af2 = *(const shortx8*)((const char*)ts +
                        mrow * (TPITCH * 2) + (s * 4 + quad) * 16);
        const int base = (s * 4 + quad) * 128 + mrow;
        #pragma unroll
        for (int n = 0; n < 8; ++n) {
            union { uint4 u; shortx8 v; } bf;
            bf.u = w2p[base + n * 16];
            acc2[n] = __builtin_amdgcn_mfma_f32_16x16x32_bf16(af2, bf.v, acc2[n], 0, 0, 0);
        }
    }

    // epilogue: residual + LayerNorm (reduce over the 16 lanes of each quad)
    float g[8], bt[8];
    #pragma unroll
    for (int n = 0; n < 8; ++n) {
        g[n]  = gamma[n * 16 + mrow];
        bt[n] = beta[n * 16 + mrow];
    }
    #pragma unroll
    for (int reg = 0; reg < 4; ++reg) {
        const int node = n0 + quad * 4 + reg;
        float u[8];
        float s1 = 0.f, s2 = 0.f;
        #pragma unroll
        for (int n = 0; n < 8; ++n) {
            u[n] = acc2[n][reg] + x[(size_t)node * D + n * 16 + mrow];
            s1 += u[n];
            s2 += u[n] * u[n];
        }
        #pragma unroll
        for (int off = 1; off < 16; off <<= 1) {
            s1 += __shfl_xor(s1, off);
            s2 += __shfl_xor(s2, off);
        }
        const float mu  = s1 * (1.f / 128.f);
        const float var = s2 * (1.f / 128.f) - mu * mu;
        const float rs  = rsqrtf(var + 1e-5f);
        #pragma unroll
        for (int n = 0; n < 8; ++n)
            out[(size_t)node * D + n * 16 + mrow] = (u[n] - mu) * rs * g[n] + bt[n];
    }
}

extern "C" void kernel_launch(void* const* d_in, const int* in_sizes, int n_in,
                              void* d_out, int out_size, void* d_ws, size_t ws_size,
                              hipStream_t stream) {
    const float* x     = (const float*)d_in[0];
    const float* pos   = (const float*)d_in[1];
    const int*   ei    = (const int*)d_in[2];
    const float* W1e   = (const float*)d_in[3];
    const float* b1e   = (const float*)d_in[4];
    const float* W2e   = (const float*)d_in[5];
    const float* b2e   = (const float*)d_in[6];
    const float* W1n   = (const float*)d_in[7];
    const float* b1n   = (const float*)d_in[8];
    const float* W2n   = (const float*)d_in[9];
    const float* b2n   = (const float*)d_in[10];
    const float* gamma = (const float*)d_in[11];
    const float* beta  = (const float*)d_in[12];
    float* out = (float*)d_out;

    // ws layout — total footprint ~116 MB.
    int*            deg    = (int*)d_ws;                              // 50176
    int*            part   = deg + 50176;
    int*            bsum   = part + 50176;
    int*            boff   = bsum + 256;
    int*            rowptr = boff + 256;                              // 50004
    int*            cursor = rowptr + 50004;                          // 50000
    // 200868 ints = 803472 B, divisible by 16 -> epack aligned
    uint4*          epack  = (uint4*)(cursor + 50000);                // 12.8 MB
    unsigned short* Abf    = (unsigned short*)(epack + NE);           // 12.8 MB
    unsigned short* Bbf    = Abf + (size_t)NND * D;                   // 12.8 MB
    unsigned short* w1f    = Bbf + (size_t)NND * D;                   // 64 KB (256x128)
    unsigned short* w1nf   = w1f + 256 * D;                           // 64 KB (256x128)
    unsigned short* w2f    = w1nf + 256 * D;                          // 32 KB (128x128)
    unsigned short* w2nf   = w2f + D * D;                             // 32 KB (128x128)
    unsigned short* wlf    = w2nf + D * D;                            // 256 B
    float*          aggf   = (float*)(wlf + 128);                     // 25.6 MB
    float*          hp     = aggf + (size_t)NND * D;                  // 25.6 MB (50000x128)
    float*          tp     = hp + (size_t)(NE / 16) * D;              // 25.6 MB

    // zero deg only
    zero_kernel<<<49, 256, 0, stream>>>((float4*)deg, 50176 / 4);

    // CSR build
    hist_kernel<<<NE / 256, 256, 0, stream>>>(ei, deg);
    scan1_kernel<<<NB1, 256, 0, stream>>>(deg, part, bsum);
    scan2_kernel<<<1, 256, 0, stream>>>(bsum, boff);
    scan3_kernel<<<197, 256, 0, stream>>>(part, boff, rowptr, cursor);
    scatter_kernel<<<NE / 256, 256, 0, stream>>>(ei, pos, cursor, epack);

    // fused weight swizzles (1 launch)
    wswzall_kernel<<<385, 256, 0, stream>>>(W1e, W1n, W2e, W2n,
                                            w1f, w1nf, w2f, w2nf, wlf);

    // A'/B precompute (MFMA, reads x f32 directly)
    precompute_kernel<<<782, 256, 0, stream>>>(x, w1f, b1e, Abf, Bbf);

    // edge MLP + in-register run reduction (interior nodes final)
    edgered_kernel<<<NE / 64, 256, 0, stream>>>(Abf, Bbf, epack, wlf, w2f, b2e,
                                                hp, tp, aggf);

    // node MLP + fused boundary stitch + residual + LN (MFMA)
    node_kernel<<<NND / 16, 64, 0, stream>>>(aggf, hp, tp, rowptr,
                                             w1nf, b1n, w2nf, b2n,
                                             x, gamma, beta, out);
}

// Round 13
// 343.901 us; speedup vs baseline: 1.1644x; 1.0002x over previous
//
#include <hip/hip_runtime.h>
#include <hip/hip_bf16.h>
#include <math.h>

#define D 128
#define NND 50000
#define NE 800000
#define NB1 196        // scan blocks: 196*256 = 50176 >= 50000
#define TPITCH 152     // ushort pitch for node transpose tile (304 B = 19*16)

typedef __attribute__((ext_vector_type(8))) short shortx8;
typedef __attribute__((ext_vector_type(4))) float floatx4;

__device__ __forceinline__ float silu_f(float v) {
    // v / (1+e^-v) with hardware rcp (1 ulp) instead of IEEE divide
    return v * __builtin_amdgcn_rcpf(1.0f + __expf(-v));
}
__device__ __forceinline__ unsigned short f2bf(float f) {
    union { float f; unsigned int u; } v; v.f = f;
    unsigned int u = v.u;
    u += 0x7fffu + ((u >> 16) & 1u);   // RNE
    return (unsigned short)(u >> 16);
}
__device__ __forceinline__ void unpk(unsigned int u, float& lo, float& hi) {
    union { unsigned int x; float f; } a, b;
    a.x = u << 16;
    b.x = u & 0xffff0000u;
    lo = a.f; hi = b.f;
}

// ---------------- CSR build ----------------
__global__ void hist_kernel(const int* __restrict__ ei, int* __restrict__ deg) {
    int e = blockIdx.x * 256 + threadIdx.x;     // NE = 3125*256 exactly
    atomicAdd(&deg[ei[e]], 1);
}

__global__ void scan1_kernel(const int* __restrict__ deg,
                             int* __restrict__ part, int* __restrict__ bsum) {
    __shared__ int s[256];
    const int tid = threadIdx.x;
    const int i = blockIdx.x * 256 + tid;
    int v = (i < NND) ? deg[i] : 0;
    s[tid] = v;
    __syncthreads();
    #pragma unroll
    for (int off = 1; off < 256; off <<= 1) {
        int t = (tid >= off) ? s[tid - off] : 0;
        __syncthreads();
        s[tid] += t;
        __syncthreads();
    }
    part[i] = s[tid] - v;                        // exclusive
    if (tid == 255) bsum[blockIdx.x] = s[255];
}

__global__ void scan2_kernel(const int* __restrict__ bsum, int* __restrict__ boff) {
    __shared__ int s[256];
    const int tid = threadIdx.x;
    int v = (tid < NB1) ? bsum[tid] : 0;
    s[tid] = v;
    __syncthreads();
    #pragma unroll
    for (int off = 1; off < 256; off <<= 1) {
        int t = (tid >= off) ? s[tid - off] : 0;
        __syncthreads();
        s[tid] += t;
        __syncthreads();
    }
    if (tid < NB1) boff[tid] = s[tid] - v;       // exclusive
}

__global__ void scan3_kernel(const int* __restrict__ part, const int* __restrict__ boff,
                             int* __restrict__ rowptr, int* __restrict__ cursor) {
    int i = blockIdx.x * 256 + threadIdx.x;
    if (i < NND) {
        int v = part[i] + boff[i >> 8];
        rowptr[i] = v;
        cursor[i] = v;
    } else if (i == NND) {
        rowptr[NND] = NE;
    }
}

// scatter packed {col, row, dist2} into CSR order: ONE 16B store per edge
__global__ void scatter_kernel(const int* __restrict__ ei, const float* __restrict__ pos,
                               int* __restrict__ cursor,
                               uint4* __restrict__ epack) {
    int e = blockIdx.x * 256 + threadIdx.x;     // NE exact multiple of 256
    int r = ei[e], c = ei[NE + e];
    float dx = pos[r * 3 + 0] - pos[c * 3 + 0];
    float dy = pos[r * 3 + 1] - pos[c * 3 + 1];
    float dz = pos[r * 3 + 2] - pos[c * 3 + 2];
    float d2 = dx * dx + dy * dy + dz * dz;
    int slot = atomicAdd(&cursor[r], 1);
    uint4 v;
    v.x = (unsigned int)c;
    v.y = (unsigned int)r;
    v.z = __float_as_uint(d2);
    v.w = 0u;
    epack[slot] = v;
}

// ---------------- fused weight swizzle (all 4 matrices + wlf, 1 launch) ----
// Wf flat f = (((ks*4+quad)*128)+n*16+mrow)*8+j  <->  W[k=ks*32+quad*8+j][col=n*16+mrow]
__global__ void wswzall_kernel(const float* __restrict__ W1e, const float* __restrict__ W1n,
                               const float* __restrict__ W2e, const float* __restrict__ W2n,
                               unsigned short* __restrict__ w1f, unsigned short* __restrict__ w1nf,
                               unsigned short* __restrict__ w2f, unsigned short* __restrict__ w2nf,
                               unsigned short* __restrict__ wlf) {
    const int b = blockIdx.x;
    const float* W; unsigned short* Wf; int lb;
    if (b < 128)      { W = W1e; Wf = w1f;  lb = b; }
    else if (b < 256) { W = W1n; Wf = w1nf; lb = b - 128; }
    else if (b < 320) { W = W2e; Wf = w2f;  lb = b - 256; }
    else if (b < 384) { W = W2n; Wf = w2nf; lb = b - 320; }
    else {
        if (threadIdx.x < 128) wlf[threadIdx.x] = f2bf(W1e[256 * D + threadIdx.x]);
        return;
    }
    int f = lb * 256 + threadIdx.x;
    int j    = f & 7;
    int mrow = (f >> 3) & 15;
    int n    = (f >> 7) & 7;
    int rest = f >> 10;
    int quad = rest & 3;
    int ks   = rest >> 2;
    int col = n * 16 + mrow;
    int k   = ks * 32 + quad * 8 + j;
    Wf[f] = f2bf(W[k * D + col]);
}

// ---------------- A' = bf16(x@W1e_top + b1e), B = bf16(x@W1e_bot)  [MFMA] ----
// reads x f32 directly, converts A-frags inline (no separate xbf pass)
__global__ __launch_bounds__(256) void precompute_kernel(
        const float* __restrict__ x,
        const unsigned short* __restrict__ w1f,   // 256x128 swizzled
        const float* __restrict__ b1e,
        unsigned short* __restrict__ A,
        unsigned short* __restrict__ Bm) {
    const int t    = threadIdx.x;
    const int wv   = t >> 6;
    const int lane = t & 63;
    const int mrow = lane & 15;
    const int quad = lane >> 4;
    const int tile = blockIdx.x * 4 + wv;
    if (tile >= 3125) return;
    const int n0 = tile * 16;

    const float4* xrow = (const float4*)(x + ((size_t)(n0 + mrow) << 7));
    const uint4* wp   = (const uint4*)w1f;

    floatx4 accA[8], accB[8];
    #pragma unroll
    for (int n = 0; n < 8; ++n) {
        accA[n] = (floatx4){0.f, 0.f, 0.f, 0.f};
        accB[n] = (floatx4){0.f, 0.f, 0.f, 0.f};
    }

    #pragma unroll
    for (int s = 0; s < 4; ++s) {
        float4 xa = xrow[(s * 4 + quad) * 2 + 0];
        float4 xb = xrow[(s * 4 + quad) * 2 + 1];
        union { shortx8 v; __hip_bfloat162 p[4]; } af;
        af.p[0] = __float22bfloat162_rn(float2{xa.x, xa.y});
        af.p[1] = __float22bfloat162_rn(float2{xa.z, xa.w});
        af.p[2] = __float22bfloat162_rn(float2{xb.x, xb.y});
        af.p[3] = __float22bfloat162_rn(float2{xb.z, xb.w});
        const int baseA = (s * 4 + quad) * 128 + mrow;
        const int baseB = ((s + 4) * 4 + quad) * 128 + mrow;
        #pragma unroll
        for (int n = 0; n < 8; ++n) {
            union { uint4 u; shortx8 v; } bfA, bfB;
            bfA.u = wp[baseA + n * 16];
            bfB.u = wp[baseB + n * 16];
            accA[n] = __builtin_amdgcn_mfma_f32_16x16x32_bf16(af.v, bfA.v, accA[n], 0, 0, 0);
            accB[n] = __builtin_amdgcn_mfma_f32_16x16x32_bf16(af.v, bfB.v, accB[n], 0, 0, 0);
        }
    }

    float bb[8];
    #pragma unroll
    for (int n = 0; n < 8; ++n) bb[n] = b1e[n * 16 + mrow];

    #pragma unroll
    for (int reg = 0; reg < 4; ++reg) {
        const int node = n0 + quad * 4 + reg;
        #pragma unroll
        for (int n = 0; n < 8; ++n) {
            const int col = n * 16 + mrow;
            A[(size_t)node * D + col]  = f2bf(accA[n][reg] + bb[n]);
            Bm[(size_t)node * D + col] = f2bf(accB[n][reg]);
        }
    }
}

// ---------------- E: edge MLP + in-register run reduction -------------------
// Wave = 16 CSR-consecutive edges (50000 tiles). After the epilogue silu each
// lane holds C[row=quad*4+reg][col=k*16+mrow] for its tile. The node-run
// structure of the 16 rows is WAVE-UNIFORM (ballot of r!=r_prev -> 16-bit
// mask), so runs are reduced in registers: 4 predicated adds + 2 shfl_xor
// per col per run (mean ~2 runs/tile). head run -> hp[tile], tail -> tp[tile],
// interior complete nodes -> aggf FINAL.
__global__ __launch_bounds__(256, 2) void edgered_kernel(
        const unsigned short* __restrict__ Abf,
        const unsigned short* __restrict__ Bbf,
        const uint4* __restrict__ epack,
        const unsigned short* __restrict__ wlf,
        const unsigned short* __restrict__ W2f,
        const float* __restrict__ b2e,
        float* __restrict__ hp,
        float* __restrict__ tp,
        float* __restrict__ aggf) {
    const int t    = threadIdx.x;
    const int wv   = t >> 6;
    const int lane = t & 63;
    const int mrow = lane & 15;
    const int quad = lane >> 4;
    const int tile = blockIdx.x * 4 + wv;       // 12500 * 4 = 50000 exact
    const int e0   = tile * 16;
    const int eme  = e0 + mrow;                 // this lane's A-frag edge

    const uint4 ep = epack[eme];                // single coalesced 16B gather
    const int   c  = (int)ep.x;
    const int   r  = (int)ep.y;                 // CSR-sorted -> L1 broadcast
    const float d2 = __uint_as_float(ep.z);

    const uint4* arow = (const uint4*)(Abf + ((size_t)r << 7));
    const uint4* brow = (const uint4*)(Bbf + ((size_t)c << 7));
    const uint4* wlq  = (const uint4*)wlf;
    const uint4* w2p  = (const uint4*)W2f;

    // hoisted loads: 12 scattered loads in flight before compute
    uint4 au[4], bu[4], wu[4];
    #pragma unroll
    for (int s = 0; s < 4; ++s) {
        au[s] = arow[s * 4 + quad];
        bu[s] = brow[s * 4 + quad];
        wu[s] = wlq[s * 4 + quad];
    }

    floatx4 acc[8];
    #pragma unroll
    for (int k = 0; k < 8; ++k) acc[k] = (floatx4){0.f, 0.f, 0.f, 0.f};

    #pragma unroll
    for (int s = 0; s < 4; ++s) {
        float a0, a1, a2, a3, a4, a5, a6, a7;
        float q0, q1, q2, q3, q4, q5, q6, q7;
        float w0, w1, w2, w3, w4, w5, w6, w7;
        unpk(au[s].x, a0, a1); unpk(au[s].y, a2, a3);
        unpk(au[s].z, a4, a5); unpk(au[s].w, a6, a7);
        unpk(bu[s].x, q0, q1); unpk(bu[s].y, q2, q3);
        unpk(bu[s].z, q4, q5); unpk(bu[s].w, q6, q7);
        unpk(wu[s].x, w0, w1); unpk(wu[s].y, w2, w3);
        unpk(wu[s].z, w4, w5); unpk(wu[s].w, w6, w7);

        float h0 = silu_f(fmaf(d2, w0, a0 + q0));
        float h1 = silu_f(fmaf(d2, w1, a1 + q1));
        float h2 = silu_f(fmaf(d2, w2, a2 + q2));
        float h3 = silu_f(fmaf(d2, w3, a3 + q3));
        float h4 = silu_f(fmaf(d2, w4, a4 + q4));
        float h5 = silu_f(fmaf(d2, w5, a5 + q5));
        float h6 = silu_f(fmaf(d2, w6, a6 + q6));
        float h7 = silu_f(fmaf(d2, w7, a7 + q7));

        union { shortx8 v; __hip_bfloat162 p[4]; } af;
        af.p[0] = __float22bfloat162_rn(float2{h0, h1});
        af.p[1] = __float22bfloat162_rn(float2{h2, h3});
        af.p[2] = __float22bfloat162_rn(float2{h4, h5});
        af.p[3] = __float22bfloat162_rn(float2{h6, h7});

        const int base = (s * 4 + quad) * 128 + mrow;
        #pragma unroll
        for (int k = 0; k < 8; ++k) {
            union { uint4 u; shortx8 v; } bf;
            bf.u = w2p[base + k * 16];
            acc[k] = __builtin_amdgcn_mfma_f32_16x16x32_bf16(af.v, bf.v, acc[k], 0, 0, 0);
        }
    }

    float bias[8];
    #pragma unroll
    for (int k = 0; k < 8; ++k) bias[k] = b2e[k * 16 + mrow];

    // second-layer silu in place
    #pragma unroll
    for (int k = 0; k < 8; ++k) {
        #pragma unroll
        for (int reg = 0; reg < 4; ++reg)
            acc[k][reg] = silu_f(acc[k][reg] + bias[k]);
    }

    // wave-uniform run mask over the 16 rows (r depends only on mrow)
    const int rp = __shfl(r, (mrow - 1) & 15);   // r of previous row
    const bool newrun = (mrow == 0) || (r != rp);
    const unsigned mask16 = (unsigned)(__ballot(newrun) & 0xffffull);

    int i = 0;
    while (i < 16) {
        const unsigned rest = mask16 & ~((1u << (i + 1)) - 1u);
        const int j = rest ? (int)__builtin_ctz(rest) : 16;  // run = rows [i,j)
        const int n = __shfl(r, i);                          // node of this run
        float s[8];
        #pragma unroll
        for (int k = 0; k < 8; ++k) {
            float v = 0.f;
            #pragma unroll
            for (int reg = 0; reg < 4; ++reg) {
                const int row = quad * 4 + reg;
                v += (row >= i && row < j) ? acc[k][reg] : 0.f;
            }
            v += __shfl_xor(v, 16);
            v += __shfl_xor(v, 32);
            s[k] = v;
        }
        if (quad == 0) {
            float* dst;
            if (i == 0)       dst = hp + (size_t)tile * 128;      // head run
            else if (j == 16) dst = tp + (size_t)tile * 128;      // tail run
            else              dst = aggf + (size_t)n * 128;       // complete
            #pragma unroll
            for (int k = 0; k < 8; ++k) dst[k * 16 + mrow] = s[k];
        }
        i = j;
    }
}

// ---------------- node MLP + residual + LayerNorm  [MFMA] ----------------
// 1 wave per block, block = 16 nodes. The boundary-node stitch is FUSED:
// each lane (mrow) classifies its node from rowptr and sources agg chunks
// directly from hp/tp/aggf (mean ~2 tiles/node). Convention: hp[t] = run
// containing row 0 of tile t; tp[t] valid iff tail run distinct.
__global__ __launch_bounds__(64) void node_kernel(
        const float* __restrict__ aggf,
        const float* __restrict__ hp,
        const float* __restrict__ tp,
        const int* __restrict__ rowptr,
        const unsigned short* __restrict__ w1nf,  // 256x128 swizzled
        const float* __restrict__ b1n,
        const unsigned short* __restrict__ w2nf,  // 128x128 swizzled
        const float* __restrict__ b2n,
        const float* __restrict__ x,
        const float* __restrict__ gamma,
        const float* __restrict__ beta,
        float* __restrict__ out) {
    __shared__ __align__(16) unsigned short ts[16 * TPITCH];
    const int lane = threadIdx.x;
    const int mrow = lane & 15;
    const int quad = lane >> 4;
    const int n0 = blockIdx.x * 16;      // 3125 blocks exact

    const float4* xrow = (const float4*)(x + ((size_t)(n0 + mrow) << 7));
    const uint4*  w1p  = (const uint4*)w1nf;
    const uint4*  w2p  = (const uint4*)w2nf;

    // classify this lane's node for the agg stitch
    const int nd = n0 + mrow;
    const int st = rowptr[nd];
    const int en = rowptr[nd + 1];
    int mode;                       // 0=empty, 1=single src, 2=multi-tile
    int t0 = 0, t1 = 0;
    const float4* gsrc = (const float4*)(aggf + ((size_t)nd << 7));
    if (st == en) {
        mode = 0;
    } else {
        t0 = st >> 4; t1 = (en - 1) >> 4;
        if (t0 == t1) {
            mode = 1;
            if ((st & 15) == 0)      gsrc = (const float4*)(hp + (size_t)t0 * 128);
            else if ((en & 15) == 0) gsrc = (const float4*)(tp + (size_t)t0 * 128);
            // else: interior run already final in aggf (gsrc default)
        } else {
            mode = 2;
        }
    }
    const float4* fsrc = ((st & 15) == 0) ? (const float4*)(hp + (size_t)t0 * 128)
                                          : (const float4*)(tp + (size_t)t0 * 128);

    floatx4 acc[8];
    #pragma unroll
    for (int n = 0; n < 8; ++n) {
        float b = b1n[n * 16 + mrow];
        acc[n] = (floatx4){b, b, b, b};
    }

    #pragma unroll
    for (int s = 0; s < 4; ++s) {
        float4 xa = xrow[(s * 4 + quad) * 2 + 0];
        float4 xb = xrow[(s * 4 + quad) * 2 + 1];
        union { shortx8 v; __hip_bfloat162 p[4]; } af;
        af.p[0] = __float22bfloat162_rn(float2{xa.x, xa.y});
        af.p[1] = __float22bfloat162_rn(float2{xa.z, xa.w});
        af.p[2] = __float22bfloat162_rn(float2{xb.x, xb.y});
        af.p[3] = __float22bfloat162_rn(float2{xb.z, xb.w});
        const int base = (s * 4 + quad) * 128 + mrow;
        #pragma unroll
        for (int n = 0; n < 8; ++n) {
            union { uint4 u; shortx8 v; } bf;
            bf.u = w1p[base + n * 16];
            acc[n] = __builtin_amdgcn_mfma_f32_16x16x32_bf16(af.v, bf.v, acc[n], 0, 0, 0);
        }
    }
    #pragma unroll
    for (int s = 0; s < 4; ++s) {
        const int ch = (s * 4 + quad) * 2;
        float4 g0, g1;
        if (mode == 0) {
            g0 = make_float4(0.f, 0.f, 0.f, 0.f);
            g1 = g0;
        } else if (mode == 1) {
            g0 = gsrc[ch + 0];
            g1 = gsrc[ch + 1];
        } else {
            g0 = fsrc[ch + 0];
            g1 = fsrc[ch + 1];
            for (int tt = t0 + 1; tt <= t1; ++tt) {  // middles + t1 = head runs
                const float4* hs = (const float4*)(hp + (size_t)tt * 128);
                float4 a = hs[ch + 0], b = hs[ch + 1];
                g0.x += a.x; g0.y += a.y; g0.z += a.z; g0.w += a.w;
                g1.x += b.x; g1.y += b.y; g1.z += b.z; g1.w += b.w;
            }
        }
        union { shortx8 v; __hip_bfloat162 p[4]; } af;
        af.p[0] = __float22bfloat162_rn(float2{g0.x, g0.y});
        af.p[1] = __float22bfloat162_rn(float2{g0.z, g0.w});
        af.p[2] = __float22bfloat162_rn(float2{g1.x, g1.y});
        af.p[3] = __float22bfloat162_rn(float2{g1.z, g1.w});
        const int base = ((s + 4) * 4 + quad) * 128 + mrow;
        #pragma unroll
        for (int n = 0; n < 8; ++n) {
            union { uint4 u; shortx8 v; } bf;
            bf.u = w1p[base + n * 16];
            acc[n] = __builtin_amdgcn_mfma_f32_16x16x32_bf16(af.v, bf.v, acc[n], 0, 0, 0);
        }
    }

    // silu -> LDS (row-major [m][col], transpose for stage-2 A-frags)
    #pragma unroll
    for (int reg = 0; reg < 4; ++reg) {
        const int m = quad * 4 + reg;
        #pragma unroll
        for (int n = 0; n < 8; ++n)
            ts[m * TPITCH + n * 16 + mrow] = f2bf(silu_f(acc[n][reg]));
    }
    __syncthreads();   // single wave: cheap; guarantees LDS RAW ordering

    floatx4 acc2[8];
    #pragma unroll
    for (int n = 0; n < 8; ++n) {
        float b = b2n[n * 16 + mrow];
        acc2[n] = (floatx4){b, b, b, b};
    }
    #pragma unroll
    for (int s = 0; s < 4; ++s) {
        shortx8 af2 = *(const shortx8*)((const char*)ts +
                        mrow * (TPITCH * 2) + (s * 4 + quad) * 16);
        const int base = (s * 4 + quad) * 128 + mrow;
        #pragma unroll
        for (int n = 0; n < 8; ++n) {
            union { uint4 u; shortx8 v; } bf;
            bf.u = w2p[base + n * 16];
            acc2[n] = __builtin_amdgcn_mfma_f32_16x16x32_bf16(af2, bf.v, acc2[n], 0, 0, 0);
        }
    }

    // epilogue: residual + LayerNorm (reduce over the 16 lanes of each quad)
    float g[8], bt[8];
    #pragma unroll
    for (int n = 0; n < 8; ++n) {
        g[n]  = gamma[n * 16 + mrow];
        bt[n] = beta[n * 16 + mrow];
    }
    #pragma unroll
    for (int reg = 0; reg < 4; ++reg) {
        const int node = n0 + quad * 4 + reg;
        float u[8];
        float s1 = 0.f, s2 = 0.f;
        #pragma unroll
        for (int n = 0; n < 8; ++n) {
            u[n] = acc2[n][reg] + x[(size_t)node * D + n * 16 + mrow];
            s1 += u[n];
            s2 += u[n] * u[n];
        }
        #pragma unroll
        for (int off = 1; off < 16; off <<= 1) {
            s1 += __shfl_xor(s1, off);
            s2 += __shfl_xor(s2, off);
        }
        const float mu  = s1 * (1.f / 128.f);
        const float var = s2 * (1.f / 128.f) - mu * mu;
        const float rs  = rsqrtf(var + 1e-5f);
        #pragma unroll
        for (int n = 0; n < 8; ++n)
            out[(size_t)node * D + n * 16 + mrow] = (u[n] - mu) * rs * g[n] + bt[n];
    }
}

extern "C" void kernel_launch(void* const* d_in, const int* in_sizes, int n_in,
                              void* d_out, int out_size, void* d_ws, size_t ws_size,
                              hipStream_t stream) {
    const float* x     = (const float*)d_in[0];
    const float* pos   = (const float*)d_in[1];
    const int*   ei    = (const int*)d_in[2];
    const float* W1e   = (const float*)d_in[3];
    const float* b1e   = (const float*)d_in[4];
    const float* W2e   = (const float*)d_in[5];
    const float* b2e   = (const float*)d_in[6];
    const float* W1n   = (const float*)d_in[7];
    const float* b1n   = (const float*)d_in[8];
    const float* W2n   = (const float*)d_in[9];
    const float* b2n   = (const float*)d_in[10];
    const float* gamma = (const float*)d_in[11];
    const float* beta  = (const float*)d_in[12];
    float* out = (float*)d_out;

    // ws layout — total footprint ~116 MB.
    int*            deg    = (int*)d_ws;                              // 50176
    int*            part   = deg + 50176;
    int*            bsum   = part + 50176;
    int*            boff   = bsum + 256;
    int*            rowptr = boff + 256;                              // 50004
    int*            cursor = rowptr + 50004;                          // 50000
    // 200868 ints = 803472 B, divisible by 16 -> epack aligned
    uint4*          epack  = (uint4*)(cursor + 50000);                // 12.8 MB
    unsigned short* Abf    = (unsigned short*)(epack + NE);           // 12.8 MB
    unsigned short* Bbf    = Abf + (size_t)NND * D;                   // 12.8 MB
    unsigned short* w1f    = Bbf + (size_t)NND * D;                   // 64 KB (256x128)
    unsigned short* w1nf   = w1f + 256 * D;                           // 64 KB (256x128)
    unsigned short* w2f    = w1nf + 256 * D;                          // 32 KB (128x128)
    unsigned short* w2nf   = w2f + D * D;                             // 32 KB (128x128)
    unsigned short* wlf    = w2nf + D * D;                            // 256 B
    float*          aggf   = (float*)(wlf + 128);                     // 25.6 MB
    float*          hp     = aggf + (size_t)NND * D;                  // 25.6 MB (50000x128)
    float*          tp     = hp + (size_t)(NE / 16) * D;              // 25.6 MB

    // zero deg (driver-optimized, capture-safe; replaces zero_kernel launch)
    hipMemsetAsync(deg, 0, 50176 * sizeof(int), stream);

    // CSR build
    hist_kernel<<<NE / 256, 256, 0, stream>>>(ei, deg);
    scan1_kernel<<<NB1, 256, 0, stream>>>(deg, part, bsum);
    scan2_kernel<<<1, 256, 0, stream>>>(bsum, boff);
    scan3_kernel<<<197, 256, 0, stream>>>(part, boff, rowptr, cursor);
    scatter_kernel<<<NE / 256, 256, 0, stream>>>(ei, pos, cursor, epack);

    // fused weight swizzles (1 launch)
    wswzall_kernel<<<385, 256, 0, stream>>>(W1e, W1n, W2e, W2n,
                                            w1f, w1nf, w2f, w2nf, wlf);

    // A'/B precompute (MFMA, reads x f32 directly)
    precompute_kernel<<<782, 256, 0, stream>>>(x, w1f, b1e, Abf, Bbf);

    // edge MLP + in-register run reduction (interior nodes final)
    edgered_kernel<<<NE / 64, 256, 0, stream>>>(Abf, Bbf, epack, wlf, w2f, b2e,
                                                hp, tp, aggf);

    // node MLP + fused boundary stitch + residual + LN (MFMA)
    node_kernel<<<NND / 16, 64, 0, stream>>>(aggf, hp, tp, rowptr,
                                             w1nf, b1n, w2nf, b2n,
                                             x, gamma, beta, out);
}